// Round 1
// 4248.422 us; speedup vs baseline: 1.0083x; 1.0083x over previous
//
#include <hip/hip_runtime.h>
#include <cstdint>
#include <cstddef>

typedef _Float16 f16;
typedef unsigned short u16;
typedef _Float16 f16x8 __attribute__((ext_vector_type(8)));
typedef float f32x4 __attribute__((ext_vector_type(4)));

#define DEV __device__ __forceinline__

DEV float b2f(u16 u) { union { float f; unsigned int i; } x; x.i = ((unsigned int)u) << 16; return x.f; }
DEV u16 f2b(float f) {
  union { float f; unsigned int i; } x; x.f = f;
  unsigned int u = x.i;
  return (u16)((u + 0x7FFFu + ((u >> 16) & 1u)) >> 16);
}
// dtype-adaptive float input read: isb=1 -> data is bf16, isb=0 -> data is fp32
DEV float ldf(const void* p, long i, int isb) {
  return isb ? b2f(((const u16*)p)[i]) : ((const float*)p)[i];
}

// async global->LDS, 16B per lane; LDS dest must be wave-uniform (HW adds lane*16)
DEV void gl_lds16(const f16* g, f16* l) {
  __builtin_amdgcn_global_load_lds((const __attribute__((address_space(1))) void*)g,
                                   (__attribute__((address_space(3))) void*)l, 16, 0, 0);
}

// ---------- input dtype detector: 1 = bf16, 0 = fp32 ----------
__global__ void detect_dtype(const u16* __restrict__ we, int* __restrict__ flag) {
  __shared__ int cnt;
  if (threadIdx.x == 0) cnt = 0;
  __syncthreads();
  int ok = 0;
  for (int i = 0; i < 16; i++) {
    u16 u = we[threadIdx.x * 16 + i];
    int e = (u >> 7) & 0xFF;  // bf16 exponent field
    if (e >= 90 && e <= 130) ok++;  // N(0,0.02) bf16 lives here; fp32 low-halves mostly don't
  }
  atomicAdd(&cnt, ok);
  __syncthreads();
  if (threadIdx.x == 0) *flag = (cnt > 3481) ? 1 : 0;  // >85% of 4096
}

// ---------- fused per-layer weight transpose: [R][C] -> f16 [C][R] ----------
__global__ __launch_bounds__(256) void transpose_layer(const void* __restrict__ Wq, const void* __restrict__ Wk,
                                                       const void* __restrict__ Wv, const void* __restrict__ Wo,
                                                       const void* __restrict__ Wf1, const void* __restrict__ Wf2,
                                                       f16* __restrict__ wt, int l, const int* __restrict__ dflag) {
  __shared__ f16 tile[32][33];
  int isb = *dflag;
  int bid = blockIdx.x;
  const void* ip;
  f16* op;
  int R, C, rblk, cblk;
  long ioff;
  if (bid < 2304) {
    int which = bid / 576, t = bid % 576;
    R = 768; C = 768;
    cblk = t % 24; rblk = t / 24;
    const void* bases[4] = {Wq, Wk, Wv, Wo};
    ip = bases[which];
    ioff = (long)l * 768 * 768;
    long outs[4] = {0, 589824, 1179648, 1769472};
    op = wt + outs[which];
  } else if (bid < 4608) {
    int t = bid - 2304;
    R = 768; C = 3072;
    cblk = t % 96; rblk = t / 96;
    ip = Wf1; ioff = (long)l * 768 * 3072;
    op = wt + 2359296;
  } else {
    int t = bid - 4608;
    R = 3072; C = 768;
    cblk = t % 24; rblk = t / 24;
    ip = Wf2; ioff = (long)l * 3072 * 768;
    op = wt + 4718592;
  }
  int r0 = rblk * 32, c0 = cblk * 32;
  int tx = threadIdx.x & 31, ty = threadIdx.x >> 5;  // 32 x 8
  for (int i = 0; i < 4; i++) {
    int r = r0 + ty + 8 * i;
    tile[ty + 8 * i][tx] = (f16)ldf(ip, ioff + (long)r * C + c0 + tx, isb);
  }
  __syncthreads();
  for (int i = 0; i < 4; i++) {
    int c = c0 + ty + 8 * i;
    op[(long)c * R + r0 + tx] = tile[tx][ty + 8 * i];
  }
}

// ---------- bias prep -> fp32, qkv fused (all 12 layers) ----------
__global__ void prep_bias(const void* bq, const void* bk, const void* bv, const void* bo,
                          const void* bf1, const void* bf2,
                          float* bqkv, float* bo_f, float* bf1f, float* bf2f, const int* dflag) {
  int isb = *dflag;
  int i = blockIdx.x * 256 + threadIdx.x;
  if (i < 12 * 768) {
    int l = i / 768, j = i % 768;
    bqkv[l * 2304 + j] = ldf(bq, i, isb);
    bqkv[l * 2304 + 768 + j] = ldf(bk, i, isb);
    bqkv[l * 2304 + 1536 + j] = ldf(bv, i, isb);
    bo_f[i] = ldf(bo, i, isb);
    bf2f[i] = ldf(bf2, i, isb);
  }
  if (i < 12 * 3072) bf1f[i] = ldf(bf1, i, isb);
}

// ---------- embedding + LN, wave per token ----------
__global__ __launch_bounds__(256) void embed_ln(const int* __restrict__ ids, const void* __restrict__ we,
                                                const void* __restrict__ pe, const void* __restrict__ te,
                                                const void* __restrict__ lw, const void* __restrict__ lb,
                                                f16* __restrict__ h, const int* __restrict__ dflag) {
  int isb = *dflag;
  int wid = threadIdx.x >> 6, lane = threadIdx.x & 63;
  long t = (long)blockIdx.x * 4 + wid;
  int s = (int)(t & 511);
  long id = ids[t];
  float v[12], s1 = 0.f, s2 = 0.f;
  for (int i = 0; i < 12; i++) {
    int j = i * 64 + lane;
    float f = ldf(we, id * 768 + j, isb) + ldf(pe, (long)s * 768 + j, isb) + ldf(te, j, isb);
    v[i] = f; s1 += f; s2 += f * f;
  }
  for (int d = 1; d < 64; d <<= 1) { s1 += __shfl_xor(s1, d, 64); s2 += __shfl_xor(s2, d, 64); }
  float mean = s1 * (1.f / 768.f);
  float var = fmaxf(s2 * (1.f / 768.f) - mean * mean, 0.f);
  float inv = rsqrtf(var + 1e-12f);
  for (int i = 0; i < 12; i++) {
    int j = i * 64 + lane;
    h[t * 768 + j] = (f16)((v[i] - mean) * inv * ldf(lw, j, isb) + ldf(lb, j, isb));
  }
}

// ---------- layernorm of f16 row; lw/lb indexed at [l][768]; FINAL=1 writes d_out ----------
template <int FINAL>
__global__ __launch_bounds__(256) void ln_row(const f16* __restrict__ x, const void* __restrict__ lw,
                                              const void* __restrict__ lb, int l, f16* __restrict__ outf,
                                              void* __restrict__ outg, const int* __restrict__ dflag) {
  int isb = *dflag;
  long poff = (long)l * 768;
  int wid = threadIdx.x >> 6, lane = threadIdx.x & 63;
  long t = (long)blockIdx.x * 4 + wid;
  const f16* xr = x + t * 768;
  float v[12], s1 = 0.f, s2 = 0.f;
  for (int i = 0; i < 12; i++) {
    float f = (float)xr[i * 64 + lane];
    v[i] = f; s1 += f; s2 += f * f;
  }
  for (int d = 1; d < 64; d <<= 1) { s1 += __shfl_xor(s1, d, 64); s2 += __shfl_xor(s2, d, 64); }
  float mean = s1 * (1.f / 768.f);
  float var = fmaxf(s2 * (1.f / 768.f) - mean * mean, 0.f);
  float inv = rsqrtf(var + 1e-12f);
  for (int i = 0; i < 12; i++) {
    int j = i * 64 + lane;
    float o = (v[i] - mean) * inv * ldf(lw, poff + j, isb) + ldf(lb, poff + j, isb);
    long idx = t * 768 + j;
    if (FINAL) {
      if (isb) ((u16*)outg)[idx] = f2b(o);
      else     ((float*)outg)[idx] = o;
    } else {
      outf[idx] = (f16)o;
    }
  }
}

// ---------- 128x128-tile GEMM: C[M,N] = A[M,K] @ Bt[N,K]^T + bias ----------
// m97 structure: async global_load_lds (16B/lane) staging, 2-barrier K-loop.
// EPI: 0 = plain, 1 = exact gelu, 2 = += resid
template <int EPI>
__global__ __launch_bounds__(256) void gemm_bt(const f16* __restrict__ A, const f16* __restrict__ Bt,
                                               const float* __restrict__ bias, const f16* __restrict__ resid,
                                               f16* __restrict__ C, int M, int N, int K) {
  __shared__ f16 lA[128 * 32];
  __shared__ f16 lB[128 * 32];
  int tid = threadIdx.x, lane = tid & 63;
  int wid = tid >> 6;
  int lm = lane & 15, quad = lane >> 4;
  int wm = wid & 1, wn = wid >> 1;

  // XCD-aware chunked swizzle: consecutive work ids (n fastest) land on ONE XCD
  // so A row-panels are fetched by a single XCD's L2. All launches have nwg%8==0.
  int gx = gridDim.x;
  int nwg = gx * gridDim.y;
  int flat = blockIdx.y * gx + blockIdx.x;
  int wgid = (flat & 7) * (nwg >> 3) + (flat >> 3);
  long m0 = (long)(wgid / gx) * 128, n0 = (long)(wgid % gx) * 128;

  f32x4 acc[4][4];
  for (int i = 0; i < 4; i++) for (int j = 0; j < 4; j++) acc[i][j] = (f32x4){0.f, 0.f, 0.f, 0.f};

  // staging: wave w covers rows [w*32, w*32+32) of the 128-row tile.
  // lane i -> row w*32 (+16 for 2nd inst) + i/4, k-part (i&3)*8; LDS dest linear.
  int srow = lane >> 2;            // 0..15
  int scol = (lane & 3) * 8;       // 0/8/16/24
  const f16* ap0 = A + (m0 + wid * 32 + srow) * (long)K + scol;
  const f16* bp0 = Bt + (n0 + wid * 32 + srow) * (long)K + scol;
  long stride16 = 16 * (long)K;
  f16* la = lA + wid * 1024;       // wave-uniform LDS bases
  f16* lb = lB + wid * 1024;

  for (int kt = 0; kt < K; kt += 32) {
    __syncthreads();               // prior iteration's ds_reads done
    gl_lds16(ap0 + kt, la);
    gl_lds16(ap0 + stride16 + kt, la + 512);
    gl_lds16(bp0 + kt, lb);
    gl_lds16(bp0 + stride16 + kt, lb + 512);
    __syncthreads();               // vmcnt(0) drain: tiles visible
    f16x8 af[4], bf[4];
    for (int mi = 0; mi < 4; mi++) af[mi] = *(const f16x8*)(lA + (wm * 64 + mi * 16 + lm) * 32 + quad * 8);
    for (int ni = 0; ni < 4; ni++) bf[ni] = *(const f16x8*)(lB + (wn * 64 + ni * 16 + lm) * 32 + quad * 8);
    for (int mi = 0; mi < 4; mi++)
      for (int ni = 0; ni < 4; ni++)
        acc[mi][ni] = __builtin_amdgcn_mfma_f32_16x16x32_f16(af[mi], bf[ni], acc[mi][ni], 0, 0, 0);
  }

  for (int mi = 0; mi < 4; mi++)
    for (int ni = 0; ni < 4; ni++) {
      long row = m0 + wm * 64 + mi * 16 + quad * 4;
      long col = n0 + wn * 64 + ni * 16 + lm;
      float bv = bias[col];
      for (int r = 0; r < 4; r++) {
        long idx = (row + r) * N + col;
        float v = acc[mi][ni][r] + bv;
        if (EPI == 1) v = 0.5f * v * (1.f + erff(v * 0.70710678118654752f));
        if (EPI == 2) v += (float)resid[idx];
        C[idx] = (f16)v;
      }
    }
}

// ---------- flash attention: block = (qtile 64 rows, head, batch), 4 waves x 16 rows ----------
__global__ __launch_bounds__(256) void attn_kern(const f16* __restrict__ qkv, const int* __restrict__ amask,
                                                 f16* __restrict__ out) {
  __shared__ f16 sK[64 * 72];      // [key][d], pad 72
  __shared__ f16 sV[64 * 72];      // [d][key] transposed, pad 72
  __shared__ f16 sP[4 * 16 * 72];  // per-wave P rows
  __shared__ float sM[64];
  int tid = threadIdx.x, wid = tid >> 6, lane = tid & 63;
  int lm = lane & 15, quad = lane >> 4;
  int qt = blockIdx.x, hh = blockIdx.y, bb = blockIdx.z;
  long tok0 = (long)bb * 512;

  const f16* qrow = qkv + (tok0 + qt * 64 + wid * 16 + lm) * 2304 + hh * 64;
  f16x8 qa0 = *(const f16x8*)(qrow + quad * 8);
  f16x8 qa1 = *(const f16x8*)(qrow + 32 + quad * 8);
  for (int j = 0; j < 8; j++) {
    qa0[j] = (f16)((float)qa0[j] * 0.125f);
    qa1[j] = (f16)((float)qa1[j] * 0.125f);
  }

  f32x4 oAcc[4];
  float mrun[4], lrun[4];
  for (int r = 0; r < 4; r++) { mrun[r] = -1e30f; lrun[r] = 0.f; }
  for (int vt = 0; vt < 4; vt++) oAcc[vt] = (f32x4){0.f, 0.f, 0.f, 0.f};
  f16* sPw = sP + wid * 16 * 72;

  for (int kt = 0; kt < 8; kt++) {
    long j0 = tok0 + kt * 64;
    __syncthreads();
    for (int rr = 0; rr < 2; rr++) {
      int g = rr * 256 + tid;
      int key = g >> 3, dp = (g & 7) * 8;
      *(f16x8*)(sK + key * 72 + dp) = *(const f16x8*)(qkv + (j0 + key) * 2304 + 768 + hh * 64 + dp);
      f16x8 vv = *(const f16x8*)(qkv + (j0 + key) * 2304 + 1536 + hh * 64 + dp);
      for (int j = 0; j < 8; j++) sV[(dp + j) * 72 + key] = vv[j];
    }
    if (tid < 64) sM[tid] = (float)amask[j0 + tid];
    __syncthreads();

    f32x4 sAcc[4];
    for (int nt = 0; nt < 4; nt++) {
      f16x8 b0 = *(const f16x8*)(sK + (nt * 16 + lm) * 72 + quad * 8);
      f16x8 b1 = *(const f16x8*)(sK + (nt * 16 + lm) * 72 + 32 + quad * 8);
      f32x4 z = (f32x4){0.f, 0.f, 0.f, 0.f};
      z = __builtin_amdgcn_mfma_f32_16x16x32_f16(qa0, b0, z, 0, 0, 0);
      z = __builtin_amdgcn_mfma_f32_16x16x32_f16(qa1, b1, z, 0, 0, 0);
      sAcc[nt] = z;
    }
    float mvv[4][4];
    for (int nt = 0; nt < 4; nt++) {
      float m = sM[nt * 16 + lm];
      for (int r = 0; r < 4; r++) mvv[nt][r] = sAcc[nt][r] * m;
    }
    for (int r = 0; r < 4; r++) {
      float mx = fmaxf(fmaxf(mvv[0][r], mvv[1][r]), fmaxf(mvv[2][r], mvv[3][r]));
      for (int d = 1; d < 16; d <<= 1) mx = fmaxf(mx, __shfl_xor(mx, d, 64));
      float mnew = fmaxf(mrun[r], mx);
      float alpha = expf(mrun[r] - mnew);
      mrun[r] = mnew;
      float rs = 0.f;
      for (int nt = 0; nt < 4; nt++) {
        float m = sM[nt * 16 + lm];
        float e = expf(mvv[nt][r] - mnew) * m;
        rs += e;
        sPw[(quad * 4 + r) * 72 + nt * 16 + lm] = (f16)e;
      }
      for (int d = 1; d < 16; d <<= 1) rs += __shfl_xor(rs, d, 64);
      lrun[r] = lrun[r] * alpha + rs;
      for (int vt = 0; vt < 4; vt++) oAcc[vt][r] *= alpha;
    }
    __syncthreads();
    f16x8 pa0 = *(const f16x8*)(sPw + lm * 72 + quad * 8);
    f16x8 pa1 = *(const f16x8*)(sPw + lm * 72 + 32 + quad * 8);
    for (int vt = 0; vt < 4; vt++) {
      f16x8 vb0 = *(const f16x8*)(sV + (vt * 16 + lm) * 72 + quad * 8);
      f16x8 vb1 = *(const f16x8*)(sV + (vt * 16 + lm) * 72 + 32 + quad * 8);
      oAcc[vt] = __builtin_amdgcn_mfma_f32_16x16x32_f16(pa0, vb0, oAcc[vt], 0, 0, 0);
      oAcc[vt] = __builtin_amdgcn_mfma_f32_16x16x32_f16(pa1, vb1, oAcc[vt], 0, 0, 0);
    }
  }
  for (int r = 0; r < 4; r++) {
    float l = lrun[r];
    l += (l == 0.f) ? 1.f : 0.f;
    float inv = 1.f / l;
    long row = tok0 + qt * 64 + wid * 16 + quad * 4 + r;
    for (int vt = 0; vt < 4; vt++)
      out[row * 768 + hh * 64 + vt * 16 + lm] = (f16)(oAcc[vt][r] * inv);
  }
}

extern "C" void kernel_launch(void* const* d_in, const int* in_sizes, int n_in,
                              void* d_out, int out_size, void* d_ws, size_t ws_size,
                              hipStream_t stream) {
  const int* ids   = (const int*)d_in[0];
  const int* amask = (const int*)d_in[1];
  const void* we  = d_in[2];
  const void* pe  = d_in[3];
  const void* te  = d_in[4];
  const void* elw = d_in[5];
  const void* elb = d_in[6];
  const void* Wq  = d_in[7];
  const void* bq  = d_in[8];
  const void* Wk  = d_in[9];
  const void* bk  = d_in[10];
  const void* Wv  = d_in[11];
  const void* bv  = d_in[12];
  const void* Wo  = d_in[13];
  const void* bo  = d_in[14];
  const void* l1w = d_in[15];
  const void* l1b = d_in[16];
  const void* Wf1 = d_in[17];
  const void* bf1 = d_in[18];
  const void* Wf2 = d_in[19];
  const void* bf2 = d_in[20];
  const void* l2w = d_in[21];
  const void* l2b = d_in[22];
  (void)in_sizes; (void)n_in; (void)out_size; (void)ws_size;

  // workspace plan (~102.6 MB)
  char* p = (char*)d_ws;
  auto alloc = [&](size_t bytes) { char* r = p; p += (bytes + 255) & ~(size_t)255; return r; };
  int* dflag  = (int*)alloc(256);
  f16* wt     = (f16*)alloc(9216ll * 768 * 2);        // per-layer transposed weights
  float* bqkv = (float*)alloc(12 * 2304 * 4);
  float* bo_f = (float*)alloc(12 * 768 * 4);
  float* bf1f = (float*)alloc(12 * 3072 * 4);
  float* bf2f = (float*)alloc(12 * 768 * 4);
  f16* hbuf  = (f16*)alloc(8192ll * 768 * 2);
  f16* h1buf = (f16*)alloc(8192ll * 768 * 2);
  f16* tmp   = (f16*)alloc(8192ll * 768 * 2);
  f16* big   = (f16*)alloc(8192ll * 3072 * 2);        // qkvb / ffn1b (+aobuf in tail)
  f16* qkvb  = big;
  f16* ffn1b = big;
  f16* aobuf = big + 8192ll * 2304;                   // tail: free during attention

  detect_dtype<<<1, 256, 0, stream>>>((const u16*)we, dflag);
  prep_bias<<<144, 256, 0, stream>>>(bq, bk, bv, bo, bf1, bf2, bqkv, bo_f, bf1f, bf2f, dflag);
  embed_ln<<<2048, 256, 0, stream>>>(ids, we, pe, te, elw, elb, hbuf, dflag);

  for (int l = 0; l < 12; ++l) {
    transpose_layer<<<6912, 256, 0, stream>>>(Wq, Wk, Wv, Wo, Wf1, Wf2, wt, l, dflag);
    gemm_bt<0><<<dim3(18, 64), 256, 0, stream>>>(hbuf, wt, bqkv + l * 2304,
                                                 nullptr, qkvb, 8192, 2304, 768);
    attn_kern<<<dim3(8, 12, 16), 256, 0, stream>>>(qkvb, amask, aobuf);
    gemm_bt<2><<<dim3(6, 64), 256, 0, stream>>>(aobuf, wt + 1769472, bo_f + l * 768,
                                                hbuf, tmp, 8192, 768, 768);
    ln_row<0><<<2048, 256, 0, stream>>>(tmp, l1w, l1b, l, h1buf, nullptr, dflag);
    gemm_bt<1><<<dim3(24, 64), 256, 0, stream>>>(h1buf, wt + 2359296, bf1f + l * 3072,
                                                 nullptr, ffn1b, 8192, 3072, 768);
    gemm_bt<2><<<dim3(6, 64), 256, 0, stream>>>(ffn1b, wt + 4718592, bf2f + l * 768,
                                                h1buf, tmp, 8192, 768, 3072);
    if (l < 11)
      ln_row<0><<<2048, 256, 0, stream>>>(tmp, l2w, l2b, l, hbuf, nullptr, dflag);
    else
      ln_row<1><<<2048, 256, 0, stream>>>(tmp, l2w, l2b, l, nullptr, d_out, dflag);
  }
}

// Round 3
// 3905.753 us; speedup vs baseline: 1.0968x; 1.0877x over previous
//
#include <hip/hip_runtime.h>
#include <cstdint>
#include <cstddef>

typedef _Float16 f16;
typedef unsigned short u16;
typedef _Float16 f16x8 __attribute__((ext_vector_type(8)));
typedef float f32x4 __attribute__((ext_vector_type(4)));

#define DEV __device__ __forceinline__

DEV float b2f(u16 u) { union { float f; unsigned int i; } x; x.i = ((unsigned int)u) << 16; return x.f; }
DEV u16 f2b(float f) {
  union { float f; unsigned int i; } x; x.f = f;
  unsigned int u = x.i;
  return (u16)((u + 0x7FFFu + ((u >> 16) & 1u)) >> 16);
}
// dtype-adaptive float input read: isb=1 -> data is bf16, isb=0 -> data is fp32
DEV float ldf(const void* p, long i, int isb) {
  return isb ? b2f(((const u16*)p)[i]) : ((const float*)p)[i];
}

// async global->LDS, 16B per lane; LDS dest must be wave-uniform (HW adds lane*16)
DEV void gl_lds16(const f16* g, f16* l) {
  __builtin_amdgcn_global_load_lds((const __attribute__((address_space(1))) void*)g,
                                   (__attribute__((address_space(3))) void*)l, 16, 0, 0);
}

// ---------- input dtype detector: 1 = bf16, 0 = fp32 ----------
__global__ void detect_dtype(const u16* __restrict__ we, int* __restrict__ flag) {
  __shared__ int cnt;
  if (threadIdx.x == 0) cnt = 0;
  __syncthreads();
  int ok = 0;
  for (int i = 0; i < 16; i++) {
    u16 u = we[threadIdx.x * 16 + i];
    int e = (u >> 7) & 0xFF;  // bf16 exponent field
    if (e >= 90 && e <= 130) ok++;  // N(0,0.02) bf16 lives here; fp32 low-halves mostly don't
  }
  atomicAdd(&cnt, ok);
  __syncthreads();
  if (threadIdx.x == 0) *flag = (cnt > 3481) ? 1 : 0;  // >85% of 4096
}

// ---------- fused per-layer weight transpose: [R][C] -> f16 [C][R] ----------
__global__ __launch_bounds__(256) void transpose_layer(const void* __restrict__ Wq, const void* __restrict__ Wk,
                                                       const void* __restrict__ Wv, const void* __restrict__ Wo,
                                                       const void* __restrict__ Wf1, const void* __restrict__ Wf2,
                                                       f16* __restrict__ wt, int l, const int* __restrict__ dflag) {
  __shared__ f16 tile[32][33];
  int isb = *dflag;
  int bid = blockIdx.x;
  const void* ip;
  f16* op;
  int R, C, rblk, cblk;
  long ioff;
  if (bid < 2304) {
    int which = bid / 576, t = bid % 576;
    R = 768; C = 768;
    cblk = t % 24; rblk = t / 24;
    const void* bases[4] = {Wq, Wk, Wv, Wo};
    ip = bases[which];
    ioff = (long)l * 768 * 768;
    long outs[4] = {0, 589824, 1179648, 1769472};
    op = wt + outs[which];
  } else if (bid < 4608) {
    int t = bid - 2304;
    R = 768; C = 3072;
    cblk = t % 96; rblk = t / 96;
    ip = Wf1; ioff = (long)l * 768 * 3072;
    op = wt + 2359296;
  } else {
    int t = bid - 4608;
    R = 3072; C = 768;
    cblk = t % 24; rblk = t / 24;
    ip = Wf2; ioff = (long)l * 3072 * 768;
    op = wt + 4718592;
  }
  int r0 = rblk * 32, c0 = cblk * 32;
  int tx = threadIdx.x & 31, ty = threadIdx.x >> 5;  // 32 x 8
  for (int i = 0; i < 4; i++) {
    int r = r0 + ty + 8 * i;
    tile[ty + 8 * i][tx] = (f16)ldf(ip, ioff + (long)r * C + c0 + tx, isb);
  }
  __syncthreads();
  for (int i = 0; i < 4; i++) {
    int c = c0 + ty + 8 * i;
    op[(long)c * R + r0 + tx] = tile[tx][ty + 8 * i];
  }
}

// ---------- bias prep -> fp32, qkv fused (all 12 layers) ----------
__global__ void prep_bias(const void* bq, const void* bk, const void* bv, const void* bo,
                          const void* bf1, const void* bf2,
                          float* bqkv, float* bo_f, float* bf1f, float* bf2f, const int* dflag) {
  int isb = *dflag;
  int i = blockIdx.x * 256 + threadIdx.x;
  if (i < 12 * 768) {
    int l = i / 768, j = i % 768;
    bqkv[l * 2304 + j] = ldf(bq, i, isb);
    bqkv[l * 2304 + 768 + j] = ldf(bk, i, isb);
    bqkv[l * 2304 + 1536 + j] = ldf(bv, i, isb);
    bo_f[i] = ldf(bo, i, isb);
    bf2f[i] = ldf(bf2, i, isb);
  }
  if (i < 12 * 3072) bf1f[i] = ldf(bf1, i, isb);
}

// ---------- embedding + LN, wave per token ----------
__global__ __launch_bounds__(256) void embed_ln(const int* __restrict__ ids, const void* __restrict__ we,
                                                const void* __restrict__ pe, const void* __restrict__ te,
                                                const void* __restrict__ lw, const void* __restrict__ lb,
                                                f16* __restrict__ h, const int* __restrict__ dflag) {
  int isb = *dflag;
  int wid = threadIdx.x >> 6, lane = threadIdx.x & 63;
  long t = (long)blockIdx.x * 4 + wid;
  int s = (int)(t & 511);
  long id = ids[t];
  float v[12], s1 = 0.f, s2 = 0.f;
  for (int i = 0; i < 12; i++) {
    int j = i * 64 + lane;
    float f = ldf(we, id * 768 + j, isb) + ldf(pe, (long)s * 768 + j, isb) + ldf(te, j, isb);
    v[i] = f; s1 += f; s2 += f * f;
  }
  for (int d = 1; d < 64; d <<= 1) { s1 += __shfl_xor(s1, d, 64); s2 += __shfl_xor(s2, d, 64); }
  float mean = s1 * (1.f / 768.f);
  float var = fmaxf(s2 * (1.f / 768.f) - mean * mean, 0.f);
  float inv = rsqrtf(var + 1e-12f);
  for (int i = 0; i < 12; i++) {
    int j = i * 64 + lane;
    h[t * 768 + j] = (f16)((v[i] - mean) * inv * ldf(lw, j, isb) + ldf(lb, j, isb));
  }
}

// ---------- layernorm of f16 row; lw/lb indexed at [l][768]; FINAL=1 writes d_out ----------
template <int FINAL>
__global__ __launch_bounds__(256) void ln_row(const f16* __restrict__ x, const void* __restrict__ lw,
                                              const void* __restrict__ lb, int l, f16* __restrict__ outf,
                                              void* __restrict__ outg, const int* __restrict__ dflag) {
  int isb = *dflag;
  long poff = (long)l * 768;
  int wid = threadIdx.x >> 6, lane = threadIdx.x & 63;
  long t = (long)blockIdx.x * 4 + wid;
  const f16* xr = x + t * 768;
  float v[12], s1 = 0.f, s2 = 0.f;
  for (int i = 0; i < 12; i++) {
    float f = (float)xr[i * 64 + lane];
    v[i] = f; s1 += f; s2 += f * f;
  }
  for (int d = 1; d < 64; d <<= 1) { s1 += __shfl_xor(s1, d, 64); s2 += __shfl_xor(s2, d, 64); }
  float mean = s1 * (1.f / 768.f);
  float var = fmaxf(s2 * (1.f / 768.f) - mean * mean, 0.f);
  float inv = rsqrtf(var + 1e-12f);
  for (int i = 0; i < 12; i++) {
    int j = i * 64 + lane;
    float o = (v[i] - mean) * inv * ldf(lw, poff + j, isb) + ldf(lb, poff + j, isb);
    long idx = t * 768 + j;
    if (FINAL) {
      if (isb) ((u16*)outg)[idx] = f2b(o);
      else     ((float*)outg)[idx] = o;
    } else {
      outf[idx] = (f16)o;
    }
  }
}

// ---------- 128x128-tile GEMM: C[M,N] = A[M,K] @ Bt[N,K]^T + bias ----------
// m97 structure: async global_load_lds (16B/lane) staging, 2-barrier K-loop.
// EPI: 0 = plain, 1 = exact gelu, 2 = += resid
template <int EPI>
__global__ __launch_bounds__(256) void gemm_bt(const f16* __restrict__ A, const f16* __restrict__ Bt,
                                               const float* __restrict__ bias, const f16* __restrict__ resid,
                                               f16* __restrict__ C, int M, int N, int K) {
  __shared__ f16 lA[128 * 32];
  __shared__ f16 lB[128 * 32];
  int tid = threadIdx.x, lane = tid & 63;
  int wid = tid >> 6;
  int lm = lane & 15, quad = lane >> 4;
  int wm = wid & 1, wn = wid >> 1;

  // XCD-aware chunked swizzle: consecutive work ids (n fastest) land on ONE XCD
  int gx = gridDim.x;
  int nwg = gx * gridDim.y;
  int flat = blockIdx.y * gx + blockIdx.x;
  int wgid = (flat & 7) * (nwg >> 3) + (flat >> 3);
  long m0 = (long)(wgid / gx) * 128, n0 = (long)(wgid % gx) * 128;

  f32x4 acc[4][4];
  for (int i = 0; i < 4; i++) for (int j = 0; j < 4; j++) acc[i][j] = (f32x4){0.f, 0.f, 0.f, 0.f};

  int srow = lane >> 2;            // 0..15
  int scol = (lane & 3) * 8;       // 0/8/16/24
  const f16* ap0 = A + (m0 + wid * 32 + srow) * (long)K + scol;
  const f16* bp0 = Bt + (n0 + wid * 32 + srow) * (long)K + scol;
  long stride16 = 16 * (long)K;
  f16* la = lA + wid * 1024;       // wave-uniform LDS bases
  f16* lb = lB + wid * 1024;

  for (int kt = 0; kt < K; kt += 32) {
    __syncthreads();               // prior iteration's ds_reads done
    gl_lds16(ap0 + kt, la);
    gl_lds16(ap0 + stride16 + kt, la + 512);
    gl_lds16(bp0 + kt, lb);
    gl_lds16(bp0 + stride16 + kt, lb + 512);
    __syncthreads();               // vmcnt(0) drain: tiles visible
    f16x8 af[4], bf[4];
    for (int mi = 0; mi < 4; mi++) af[mi] = *(const f16x8*)(lA + (wm * 64 + mi * 16 + lm) * 32 + quad * 8);
    for (int ni = 0; ni < 4; ni++) bf[ni] = *(const f16x8*)(lB + (wn * 64 + ni * 16 + lm) * 32 + quad * 8);
    for (int mi = 0; mi < 4; mi++)
      for (int ni = 0; ni < 4; ni++)
        acc[mi][ni] = __builtin_amdgcn_mfma_f32_16x16x32_f16(af[mi], bf[ni], acc[mi][ni], 0, 0, 0);
  }

  for (int mi = 0; mi < 4; mi++)
    for (int ni = 0; ni < 4; ni++) {
      long row = m0 + wm * 64 + mi * 16 + quad * 4;
      long col = n0 + wn * 64 + ni * 16 + lm;
      float bv = bias[col];
      for (int r = 0; r < 4; r++) {
        long idx = (row + r) * N + col;
        float v = acc[mi][ni][r] + bv;
        if (EPI == 1) v = 0.5f * v * (1.f + erff(v * 0.70710678118654752f));
        if (EPI == 2) v += (float)resid[idx];
        C[idx] = (f16)v;
      }
    }
}

// ---------- V transpose: qkvb V-part [token][768] -> vT [768][8192] ----------
// block = (stile, head, batch); 64x64 tile via padded LDS
__global__ __launch_bounds__(256) void vtrans(const f16* __restrict__ qkv, f16* __restrict__ vT) {
  __shared__ f16 sT[64 * 72];
  int tid = threadIdx.x;
  int st = blockIdx.x, hh = blockIdx.y, bb = blockIdx.z;
  long t0 = (long)bb * 512 + st * 64;
  int r = tid >> 3, c = tid & 7;  // r 0..31, c = 16B chunk
  const f16* src = qkv + 1536 + (long)hh * 64 + c * 8;
  *(f16x8*)(sT + r * 72 + c * 8)      = *(const f16x8*)(src + (t0 + r) * 2304);
  *(f16x8*)(sT + (r + 32) * 72 + c * 8) = *(const f16x8*)(src + (t0 + r + 32) * 2304);
  __syncthreads();
  int d = tid >> 2, sq = tid & 3;  // d 0..63, sq: 16-token chunk
  f16 tmp[16];
  for (int j = 0; j < 16; j++) tmp[j] = sT[(sq * 16 + j) * 72 + d];
  f16x8* o = (f16x8*)(vT + ((long)hh * 64 + d) * 8192 + t0 + sq * 16);
  o[0] = *(f16x8*)(tmp);
  o[1] = *(f16x8*)(tmp + 8);
}

// ---------- flash attention v2 ----------
// block = (hh + 12*bb, qt): qt-blocks of one head are 192 apart in flat id -> same XCD (L2 reuse).
// K and V^T staged via global_load_lds with XOR-preswizzled source (rule #21), zero write conflicts.
__global__ __launch_bounds__(256) void attn_kern(const f16* __restrict__ qkv, const f16* __restrict__ vT,
                                                 const int* __restrict__ amask, f16* __restrict__ out) {
  __shared__ f16 sK[64 * 64];      // [key][d], XOR-swizzled: col^=(key&7)*8
  __shared__ f16 sVT[64 * 64];     // [d][key], XOR-swizzled: col^=(d&7)*8
  __shared__ f16 sP[4 * 16 * 72];  // per-wave P rows
  __shared__ float sMall[512];
  int tid = threadIdx.x, wid = tid >> 6, lane = tid & 63;
  int lm = lane & 15, quad = lane >> 4;
  int xb = blockIdx.x, qt = blockIdx.y;
  int hh = xb % 12, bb = xb / 12;
  long tok0 = (long)bb * 512;

  sMall[tid] = (float)amask[tok0 + tid];
  sMall[tid + 256] = (float)amask[tok0 + 256 + tid];

  const f16* qrow = qkv + (tok0 + qt * 64 + wid * 16 + lm) * 2304 + hh * 64;
  f16x8 qa0 = *(const f16x8*)(qrow + quad * 8);
  f16x8 qa1 = *(const f16x8*)(qrow + 32 + quad * 8);
  for (int j = 0; j < 8; j++) {
    qa0[j] = (f16)((float)qa0[j] * 0.125f);
    qa1[j] = (f16)((float)qa1[j] * 0.125f);
  }

  f32x4 oAcc[4];
  float mrun[4], lrun[4];
  for (int r = 0; r < 4; r++) { mrun[r] = -1e30f; lrun[r] = 0.f; }
  for (int vt = 0; vt < 4; vt++) oAcc[vt] = (f32x4){0.f, 0.f, 0.f, 0.f};
  f16* sPw = sP + wid * 16 * 72;
  int swl = (lm & 7) * 8;                        // read-side XOR (elems)

  // staging: wave w issues instrs i=2w,2w+1 for K and V^T (8 rows each, 128B/row)
  int i0 = wid * 2;
  int key0 = lane >> 3;                          // 0..7
  int col = ((lane & 7) ^ (lane >> 3)) * 8;      // pre-swizzled source col (elems)
  const f16* kb0 = qkv + 768 + (long)hh * 64 + col;
  const f16* vb0 = vT + ((long)hh * 64) * 8192 + tok0 + col;

  for (int kt = 0; kt < 8; kt++) {
    long j0 = tok0 + kt * 64;
    __syncthreads();  // prior iteration's sK/sVT reads done (also covers sMall first use)
    for (int ii = 0; ii < 2; ii++) {
      int i = i0 + ii;
      int rowi = i * 8 + key0;
      gl_lds16(kb0 + (j0 + rowi) * 2304, sK + i * 512);
      gl_lds16(vb0 + (long)rowi * 8192 + kt * 64, sVT + i * 512);
    }
    __syncthreads();  // vmcnt(0) drain: tiles visible

    f32x4 sAcc[4];
    for (int nt = 0; nt < 4; nt++) {
      const f16* kr = sK + (nt * 16 + lm) * 64;
      f16x8 b0 = *(const f16x8*)(kr + ((quad * 8) ^ swl));
      f16x8 b1 = *(const f16x8*)(kr + ((32 + quad * 8) ^ swl));
      f32x4 z = (f32x4){0.f, 0.f, 0.f, 0.f};
      z = __builtin_amdgcn_mfma_f32_16x16x32_f16(qa0, b0, z, 0, 0, 0);
      z = __builtin_amdgcn_mfma_f32_16x16x32_f16(qa1, b1, z, 0, 0, 0);
      sAcc[nt] = z;
    }
    float mk[4];
    for (int nt = 0; nt < 4; nt++) mk[nt] = sMall[kt * 64 + nt * 16 + lm];
    float mvv[4][4];
    for (int nt = 0; nt < 4; nt++)
      for (int r = 0; r < 4; r++) mvv[nt][r] = sAcc[nt][r] * mk[nt];
    for (int r = 0; r < 4; r++) {
      float mx = fmaxf(fmaxf(mvv[0][r], mvv[1][r]), fmaxf(mvv[2][r], mvv[3][r]));
      for (int d = 1; d < 16; d <<= 1) mx = fmaxf(mx, __shfl_xor(mx, d, 64));
      float mnew = fmaxf(mrun[r], mx);
      float alpha = __expf(mrun[r] - mnew);
      mrun[r] = mnew;
      float rs = 0.f;
      for (int nt = 0; nt < 4; nt++) {
        float e = __expf(mvv[nt][r] - mnew) * mk[nt];
        rs += e;
        sPw[(quad * 4 + r) * 72 + nt * 16 + lm] = (f16)e;
      }
      for (int d = 1; d < 16; d <<= 1) rs += __shfl_xor(rs, d, 64);
      lrun[r] = lrun[r] * alpha + rs;
      for (int vt = 0; vt < 4; vt++) oAcc[vt][r] *= alpha;
    }
    // same-wave sP RAW is lgkmcnt-ordered; no cross-wave hazard -> no barrier here
    f16x8 pa0 = *(const f16x8*)(sPw + lm * 72 + quad * 8);
    f16x8 pa1 = *(const f16x8*)(sPw + lm * 72 + 32 + quad * 8);
    for (int vt = 0; vt < 4; vt++) {
      const f16* vr = sVT + (vt * 16 + lm) * 64;
      f16x8 vb0f = *(const f16x8*)(vr + ((quad * 8) ^ swl));
      f16x8 vb1f = *(const f16x8*)(vr + ((32 + quad * 8) ^ swl));
      oAcc[vt] = __builtin_amdgcn_mfma_f32_16x16x32_f16(pa0, vb0f, oAcc[vt], 0, 0, 0);
      oAcc[vt] = __builtin_amdgcn_mfma_f32_16x16x32_f16(pa1, vb1f, oAcc[vt], 0, 0, 0);
    }
  }
  for (int r = 0; r < 4; r++) {
    float l = lrun[r];
    l += (l == 0.f) ? 1.f : 0.f;
    float inv = 1.f / l;
    long row = tok0 + qt * 64 + wid * 16 + quad * 4 + r;
    for (int vt = 0; vt < 4; vt++)
      out[row * 768 + hh * 64 + vt * 16 + lm] = (f16)(oAcc[vt][r] * inv);
  }
}

extern "C" void kernel_launch(void* const* d_in, const int* in_sizes, int n_in,
                              void* d_out, int out_size, void* d_ws, size_t ws_size,
                              hipStream_t stream) {
  const int* ids   = (const int*)d_in[0];
  const int* amask = (const int*)d_in[1];
  const void* we  = d_in[2];
  const void* pe  = d_in[3];
  const void* te  = d_in[4];
  const void* elw = d_in[5];
  const void* elb = d_in[6];
  const void* Wq  = d_in[7];
  const void* bq  = d_in[8];
  const void* Wk  = d_in[9];
  const void* bk  = d_in[10];
  const void* Wv  = d_in[11];
  const void* bv  = d_in[12];
  const void* Wo  = d_in[13];
  const void* bo  = d_in[14];
  const void* l1w = d_in[15];
  const void* l1b = d_in[16];
  const void* Wf1 = d_in[17];
  const void* bf1 = d_in[18];
  const void* Wf2 = d_in[19];
  const void* bf2 = d_in[20];
  const void* l2w = d_in[21];
  const void* l2b = d_in[22];
  (void)in_sizes; (void)n_in; (void)out_size; (void)ws_size;

  // workspace plan (~102.6 MB)
  char* p = (char*)d_ws;
  auto alloc = [&](size_t bytes) { char* r = p; p += (bytes + 255) & ~(size_t)255; return r; };
  int* dflag  = (int*)alloc(256);
  f16* wt     = (f16*)alloc(9216ll * 768 * 2);        // per-layer transposed weights
  float* bqkv = (float*)alloc(12 * 2304 * 4);
  float* bo_f = (float*)alloc(12 * 768 * 4);
  float* bf1f = (float*)alloc(12 * 3072 * 4);
  float* bf2f = (float*)alloc(12 * 768 * 4);
  f16* hbuf  = (f16*)alloc(8192ll * 768 * 2);
  f16* h1buf = (f16*)alloc(8192ll * 768 * 2);
  f16* tmp   = (f16*)alloc(8192ll * 768 * 2);         // doubles as vT during attention
  f16* big   = (f16*)alloc(8192ll * 3072 * 2);        // qkvb / ffn1b (+aobuf in tail)
  f16* qkvb  = big;
  f16* ffn1b = big;
  f16* aobuf = big + 8192ll * 2304;                   // tail: free during attention

  detect_dtype<<<1, 256, 0, stream>>>((const u16*)we, dflag);
  prep_bias<<<144, 256, 0, stream>>>(bq, bk, bv, bo, bf1, bf2, bqkv, bo_f, bf1f, bf2f, dflag);
  embed_ln<<<2048, 256, 0, stream>>>(ids, we, pe, te, elw, elb, hbuf, dflag);

  for (int l = 0; l < 12; ++l) {
    transpose_layer<<<6912, 256, 0, stream>>>(Wq, Wk, Wv, Wo, Wf1, Wf2, wt, l, dflag);
    gemm_bt<0><<<dim3(18, 64), 256, 0, stream>>>(hbuf, wt, bqkv + l * 2304,
                                                 nullptr, qkvb, 8192, 2304, 768);
    vtrans<<<dim3(8, 12, 16), 256, 0, stream>>>(qkvb, tmp);
    attn_kern<<<dim3(192, 8), 256, 0, stream>>>(qkvb, tmp, amask, aobuf);
    gemm_bt<2><<<dim3(6, 64), 256, 0, stream>>>(aobuf, wt + 1769472, bo_f + l * 768,
                                                hbuf, tmp, 8192, 768, 768);
    ln_row<0><<<2048, 256, 0, stream>>>(tmp, l1w, l1b, l, h1buf, nullptr, dflag);
    gemm_bt<1><<<dim3(24, 64), 256, 0, stream>>>(h1buf, wt + 2359296, bf1f + l * 3072,
                                                 nullptr, ffn1b, 8192, 3072, 768);
    gemm_bt<2><<<dim3(6, 64), 256, 0, stream>>>(ffn1b, wt + 4718592, bf2f + l * 768,
                                                h1buf, tmp, 8192, 768, 3072);
    if (l < 11)
      ln_row<0><<<2048, 256, 0, stream>>>(tmp, l2w, l2b, l, hbuf, nullptr, dflag);
    else
      ln_row<1><<<2048, 256, 0, stream>>>(tmp, l2w, l2b, l, nullptr, d_out, dflag);
  }
}

// Round 4
// 3752.235 us; speedup vs baseline: 1.1417x; 1.0409x over previous
//
#include <hip/hip_runtime.h>
#include <cstdint>
#include <cstddef>

typedef _Float16 f16;
typedef unsigned short u16;
typedef _Float16 f16x8 __attribute__((ext_vector_type(8)));
typedef float f32x4 __attribute__((ext_vector_type(4)));

#define DEV __device__ __forceinline__

DEV float b2f(u16 u) { union { float f; unsigned int i; } x; x.i = ((unsigned int)u) << 16; return x.f; }
DEV u16 f2b(float f) {
  union { float f; unsigned int i; } x; x.f = f;
  unsigned int u = x.i;
  return (u16)((u + 0x7FFFu + ((u >> 16) & 1u)) >> 16);
}
// dtype-adaptive float input read: isb=1 -> data is bf16, isb=0 -> data is fp32
DEV float ldf(const void* p, long i, int isb) {
  return isb ? b2f(((const u16*)p)[i]) : ((const float*)p)[i];
}

// async global->LDS, 16B per lane; LDS dest must be wave-uniform (HW adds lane*16)
DEV void gl_lds16(const f16* g, f16* l) {
  __builtin_amdgcn_global_load_lds((const __attribute__((address_space(1))) void*)g,
                                   (__attribute__((address_space(3))) void*)l, 16, 0, 0);
}

// ---------- input dtype detector: 1 = bf16, 0 = fp32 ----------
__global__ void detect_dtype(const u16* __restrict__ we, int* __restrict__ flag) {
  __shared__ int cnt;
  if (threadIdx.x == 0) cnt = 0;
  __syncthreads();
  int ok = 0;
  for (int i = 0; i < 16; i++) {
    u16 u = we[threadIdx.x * 16 + i];
    int e = (u >> 7) & 0xFF;  // bf16 exponent field
    if (e >= 90 && e <= 130) ok++;  // N(0,0.02) bf16 lives here; fp32 low-halves mostly don't
  }
  atomicAdd(&cnt, ok);
  __syncthreads();
  if (threadIdx.x == 0) *flag = (cnt > 3481) ? 1 : 0;  // >85% of 4096
}

// ---------- fused per-layer weight transpose: [R][C] -> f16 [C][R] ----------
__global__ __launch_bounds__(256) void transpose_layer(const void* __restrict__ Wq, const void* __restrict__ Wk,
                                                       const void* __restrict__ Wv, const void* __restrict__ Wo,
                                                       const void* __restrict__ Wf1, const void* __restrict__ Wf2,
                                                       f16* __restrict__ wt, int l, const int* __restrict__ dflag) {
  __shared__ f16 tile[32][33];
  int isb = *dflag;
  int bid = blockIdx.x;
  const void* ip;
  f16* op;
  int R, C, rblk, cblk;
  long ioff;
  if (bid < 2304) {
    int which = bid / 576, t = bid % 576;
    R = 768; C = 768;
    cblk = t % 24; rblk = t / 24;
    const void* bases[4] = {Wq, Wk, Wv, Wo};
    ip = bases[which];
    ioff = (long)l * 768 * 768;
    long outs[4] = {0, 589824, 1179648, 1769472};
    op = wt + outs[which];
  } else if (bid < 4608) {
    int t = bid - 2304;
    R = 768; C = 3072;
    cblk = t % 96; rblk = t / 96;
    ip = Wf1; ioff = (long)l * 768 * 3072;
    op = wt + 2359296;
  } else {
    int t = bid - 4608;
    R = 3072; C = 768;
    cblk = t % 24; rblk = t / 24;
    ip = Wf2; ioff = (long)l * 3072 * 768;
    op = wt + 4718592;
  }
  int r0 = rblk * 32, c0 = cblk * 32;
  int tx = threadIdx.x & 31, ty = threadIdx.x >> 5;  // 32 x 8
  for (int i = 0; i < 4; i++) {
    int r = r0 + ty + 8 * i;
    tile[ty + 8 * i][tx] = (f16)ldf(ip, ioff + (long)r * C + c0 + tx, isb);
  }
  __syncthreads();
  for (int i = 0; i < 4; i++) {
    int c = c0 + ty + 8 * i;
    op[(long)c * R + r0 + tx] = tile[tx][ty + 8 * i];
  }
}

// ---------- bias prep -> fp32, qkv fused (all 12 layers) ----------
__global__ void prep_bias(const void* bq, const void* bk, const void* bv, const void* bo,
                          const void* bf1, const void* bf2,
                          float* bqkv, float* bo_f, float* bf1f, float* bf2f, const int* dflag) {
  int isb = *dflag;
  int i = blockIdx.x * 256 + threadIdx.x;
  if (i < 12 * 768) {
    int l = i / 768, j = i % 768;
    bqkv[l * 2304 + j] = ldf(bq, i, isb);
    bqkv[l * 2304 + 768 + j] = ldf(bk, i, isb);
    bqkv[l * 2304 + 1536 + j] = ldf(bv, i, isb);
    bo_f[i] = ldf(bo, i, isb);
    bf2f[i] = ldf(bf2, i, isb);
  }
  if (i < 12 * 3072) bf1f[i] = ldf(bf1, i, isb);
}

// ---------- embedding + LN, wave per token ----------
__global__ __launch_bounds__(256) void embed_ln(const int* __restrict__ ids, const void* __restrict__ we,
                                                const void* __restrict__ pe, const void* __restrict__ te,
                                                const void* __restrict__ lw, const void* __restrict__ lb,
                                                f16* __restrict__ h, const int* __restrict__ dflag) {
  int isb = *dflag;
  int wid = threadIdx.x >> 6, lane = threadIdx.x & 63;
  long t = (long)blockIdx.x * 4 + wid;
  int s = (int)(t & 511);
  long id = ids[t];
  float v[12], s1 = 0.f, s2 = 0.f;
  for (int i = 0; i < 12; i++) {
    int j = i * 64 + lane;
    float f = ldf(we, id * 768 + j, isb) + ldf(pe, (long)s * 768 + j, isb) + ldf(te, j, isb);
    v[i] = f; s1 += f; s2 += f * f;
  }
  for (int d = 1; d < 64; d <<= 1) { s1 += __shfl_xor(s1, d, 64); s2 += __shfl_xor(s2, d, 64); }
  float mean = s1 * (1.f / 768.f);
  float var = fmaxf(s2 * (1.f / 768.f) - mean * mean, 0.f);
  float inv = rsqrtf(var + 1e-12f);
  for (int i = 0; i < 12; i++) {
    int j = i * 64 + lane;
    h[t * 768 + j] = (f16)((v[i] - mean) * inv * ldf(lw, j, isb) + ldf(lb, j, isb));
  }
}

// ---------- layernorm of f16 row; lw/lb indexed at [l][768]; FINAL=1 writes d_out ----------
template <int FINAL>
__global__ __launch_bounds__(256) void ln_row(const f16* __restrict__ x, const void* __restrict__ lw,
                                              const void* __restrict__ lb, int l, f16* __restrict__ outf,
                                              void* __restrict__ outg, const int* __restrict__ dflag) {
  int isb = *dflag;
  long poff = (long)l * 768;
  int wid = threadIdx.x >> 6, lane = threadIdx.x & 63;
  long t = (long)blockIdx.x * 4 + wid;
  const f16* xr = x + t * 768;
  float v[12], s1 = 0.f, s2 = 0.f;
  for (int i = 0; i < 12; i++) {
    float f = (float)xr[i * 64 + lane];
    v[i] = f; s1 += f; s2 += f * f;
  }
  for (int d = 1; d < 64; d <<= 1) { s1 += __shfl_xor(s1, d, 64); s2 += __shfl_xor(s2, d, 64); }
  float mean = s1 * (1.f / 768.f);
  float var = fmaxf(s2 * (1.f / 768.f) - mean * mean, 0.f);
  float inv = rsqrtf(var + 1e-12f);
  for (int i = 0; i < 12; i++) {
    int j = i * 64 + lane;
    float o = (v[i] - mean) * inv * ldf(lw, poff + j, isb) + ldf(lb, poff + j, isb);
    long idx = t * 768 + j;
    if (FINAL) {
      if (isb) ((u16*)outg)[idx] = f2b(o);
      else     ((float*)outg)[idx] = o;
    } else {
      outf[idx] = (f16)o;
    }
  }
}

// ---------- 128x128-tile GEMM: C[M,N] = A[M,K] @ Bt[N,K]^T + bias ----------
// 2-phase double-buffered pipeline (T3 minimum): issue next tile's global_load_lds
// BEFORE computing current tile; one __syncthreads per K-step (its builtin
// vmcnt(0)+lgkmcnt(0) drain IS the "vmcnt(0); barrier" of the recipe).
// EPI: 0 = plain, 1 = exact gelu, 2 = += resid
template <int EPI>
__global__ __launch_bounds__(256) void gemm_bt(const f16* __restrict__ A, const f16* __restrict__ Bt,
                                               const float* __restrict__ bias, const f16* __restrict__ resid,
                                               f16* __restrict__ C, int M, int N, int K) {
  __shared__ f16 lA[2][128 * 32];
  __shared__ f16 lB[2][128 * 32];
  int tid = threadIdx.x, lane = tid & 63;
  int wid = tid >> 6;
  int lm = lane & 15, quad = lane >> 4;
  int wm = wid & 1, wn = wid >> 1;

  // XCD-aware chunked swizzle: consecutive work ids (n fastest) land on ONE XCD
  int gx = gridDim.x;
  int nwg = gx * gridDim.y;
  int flat = blockIdx.y * gx + blockIdx.x;
  int wgid = (flat & 7) * (nwg >> 3) + (flat >> 3);
  long m0 = (long)(wgid / gx) * 128, n0 = (long)(wgid % gx) * 128;

  f32x4 acc[4][4];
  for (int i = 0; i < 4; i++) for (int j = 0; j < 4; j++) acc[i][j] = (f32x4){0.f, 0.f, 0.f, 0.f};

  // staging: wave w covers rows [w*32, w*32+32); lane i -> row w*32(+16) + i/4, k (i&3)*8
  int srow = lane >> 2;            // 0..15
  int scol = (lane & 3) * 8;       // 0/8/16/24
  const f16* ap0 = A + (m0 + wid * 32 + srow) * (long)K + scol;
  const f16* bp0 = Bt + (n0 + wid * 32 + srow) * (long)K + scol;
  long stride16 = 16 * (long)K;

  auto stage = [&](int buf, int kt) {
    f16* la = lA[buf] + wid * 1024;  // wave-uniform LDS bases
    f16* lb = lB[buf] + wid * 1024;
    gl_lds16(ap0 + kt, la);
    gl_lds16(ap0 + stride16 + kt, la + 512);
    gl_lds16(bp0 + kt, lb);
    gl_lds16(bp0 + stride16 + kt, lb + 512);
  };

  stage(0, 0);
  int cur = 0;
  for (int kt = 0; kt < K; kt += 32) {
    __syncthreads();               // vmcnt(0)+lgkmcnt(0)+barrier: buf[cur] loads landed,
                                   // all waves done reading buf[cur^1] (lgkm drained pre-MFMA)
    if (kt + 32 < K) stage(cur ^ 1, kt + 32);  // prefetch next tile under this tile's compute
    f16x8 af[4], bf[4];
    for (int mi = 0; mi < 4; mi++) af[mi] = *(const f16x8*)(lA[cur] + (wm * 64 + mi * 16 + lm) * 32 + quad * 8);
    for (int ni = 0; ni < 4; ni++) bf[ni] = *(const f16x8*)(lB[cur] + (wn * 64 + ni * 16 + lm) * 32 + quad * 8);
    for (int mi = 0; mi < 4; mi++)
      for (int ni = 0; ni < 4; ni++)
        acc[mi][ni] = __builtin_amdgcn_mfma_f32_16x16x32_f16(af[mi], bf[ni], acc[mi][ni], 0, 0, 0);
    cur ^= 1;
  }

  for (int mi = 0; mi < 4; mi++)
    for (int ni = 0; ni < 4; ni++) {
      long row = m0 + wm * 64 + mi * 16 + quad * 4;
      long col = n0 + wn * 64 + ni * 16 + lm;
      float bv = bias[col];
      for (int r = 0; r < 4; r++) {
        long idx = (row + r) * N + col;
        float v = acc[mi][ni][r] + bv;
        if (EPI == 1) v = 0.5f * v * (1.f + erff(v * 0.70710678118654752f));
        if (EPI == 2) v += (float)resid[idx];
        C[idx] = (f16)v;
      }
    }
}

// ---------- V transpose: qkvb V-part [token][768] -> vT [768][8192] ----------
// block = (stile, head, batch); 64x64 tile via padded LDS
__global__ __launch_bounds__(256) void vtrans(const f16* __restrict__ qkv, f16* __restrict__ vT) {
  __shared__ f16 sT[64 * 72];
  int tid = threadIdx.x;
  int st = blockIdx.x, hh = blockIdx.y, bb = blockIdx.z;
  long t0 = (long)bb * 512 + st * 64;
  int r = tid >> 3, c = tid & 7;  // r 0..31, c = 16B chunk
  const f16* src = qkv + 1536 + (long)hh * 64 + c * 8;
  *(f16x8*)(sT + r * 72 + c * 8)      = *(const f16x8*)(src + (t0 + r) * 2304);
  *(f16x8*)(sT + (r + 32) * 72 + c * 8) = *(const f16x8*)(src + (t0 + r + 32) * 2304);
  __syncthreads();
  int d = tid >> 2, sq = tid & 3;  // d 0..63, sq: 16-token chunk
  f16 tmp[16];
  for (int j = 0; j < 16; j++) tmp[j] = sT[(sq * 16 + j) * 72 + d];
  f16x8* o = (f16x8*)(vT + ((long)hh * 64 + d) * 8192 + t0 + sq * 16);
  o[0] = *(f16x8*)(tmp);
  o[1] = *(f16x8*)(tmp + 8);
}

// ---------- flash attention v2 ----------
// block = (hh + 12*bb, qt): qt-blocks of one head are 192 apart in flat id -> same XCD (L2 reuse).
// K and V^T staged via global_load_lds with XOR-preswizzled source (rule #21), zero write conflicts.
__global__ __launch_bounds__(256) void attn_kern(const f16* __restrict__ qkv, const f16* __restrict__ vT,
                                                 const int* __restrict__ amask, f16* __restrict__ out) {
  __shared__ f16 sK[64 * 64];      // [key][d], XOR-swizzled: col^=(key&7)*8
  __shared__ f16 sVT[64 * 64];     // [d][key], XOR-swizzled: col^=(d&7)*8
  __shared__ f16 sP[4 * 16 * 72];  // per-wave P rows
  __shared__ float sMall[512];
  int tid = threadIdx.x, wid = tid >> 6, lane = tid & 63;
  int lm = lane & 15, quad = lane >> 4;
  int xb = blockIdx.x, qt = blockIdx.y;
  int hh = xb % 12, bb = xb / 12;
  long tok0 = (long)bb * 512;

  sMall[tid] = (float)amask[tok0 + tid];
  sMall[tid + 256] = (float)amask[tok0 + 256 + tid];

  const f16* qrow = qkv + (tok0 + qt * 64 + wid * 16 + lm) * 2304 + hh * 64;
  f16x8 qa0 = *(const f16x8*)(qrow + quad * 8);
  f16x8 qa1 = *(const f16x8*)(qrow + 32 + quad * 8);
  for (int j = 0; j < 8; j++) {
    qa0[j] = (f16)((float)qa0[j] * 0.125f);
    qa1[j] = (f16)((float)qa1[j] * 0.125f);
  }

  f32x4 oAcc[4];
  float mrun[4], lrun[4];
  for (int r = 0; r < 4; r++) { mrun[r] = -1e30f; lrun[r] = 0.f; }
  for (int vt = 0; vt < 4; vt++) oAcc[vt] = (f32x4){0.f, 0.f, 0.f, 0.f};
  f16* sPw = sP + wid * 16 * 72;
  int swl = (lm & 7) * 8;                        // read-side XOR (elems)

  // staging: wave w issues instrs i=2w,2w+1 for K and V^T (8 rows each, 128B/row)
  int i0 = wid * 2;
  int key0 = lane >> 3;                          // 0..7
  int col = ((lane & 7) ^ (lane >> 3)) * 8;      // pre-swizzled source col (elems)
  const f16* kb0 = qkv + 768 + (long)hh * 64 + col;
  const f16* vb0 = vT + ((long)hh * 64) * 8192 + tok0 + col;

  for (int kt = 0; kt < 8; kt++) {
    long j0 = tok0 + kt * 64;
    __syncthreads();  // prior iteration's sK/sVT reads done (also covers sMall first use)
    for (int ii = 0; ii < 2; ii++) {
      int i = i0 + ii;
      int rowi = i * 8 + key0;
      gl_lds16(kb0 + (j0 + rowi) * 2304, sK + i * 512);
      gl_lds16(vb0 + (long)rowi * 8192 + kt * 64, sVT + i * 512);
    }
    __syncthreads();  // vmcnt(0) drain: tiles visible

    f32x4 sAcc[4];
    for (int nt = 0; nt < 4; nt++) {
      const f16* kr = sK + (nt * 16 + lm) * 64;
      f16x8 b0 = *(const f16x8*)(kr + ((quad * 8) ^ swl));
      f16x8 b1 = *(const f16x8*)(kr + ((32 + quad * 8) ^ swl));
      f32x4 z = (f32x4){0.f, 0.f, 0.f, 0.f};
      z = __builtin_amdgcn_mfma_f32_16x16x32_f16(qa0, b0, z, 0, 0, 0);
      z = __builtin_amdgcn_mfma_f32_16x16x32_f16(qa1, b1, z, 0, 0, 0);
      sAcc[nt] = z;
    }
    float mk[4];
    for (int nt = 0; nt < 4; nt++) mk[nt] = sMall[kt * 64 + nt * 16 + lm];
    float mvv[4][4];
    for (int nt = 0; nt < 4; nt++)
      for (int r = 0; r < 4; r++) mvv[nt][r] = sAcc[nt][r] * mk[nt];
    for (int r = 0; r < 4; r++) {
      float mx = fmaxf(fmaxf(mvv[0][r], mvv[1][r]), fmaxf(mvv[2][r], mvv[3][r]));
      for (int d = 1; d < 16; d <<= 1) mx = fmaxf(mx, __shfl_xor(mx, d, 64));
      float mnew = fmaxf(mrun[r], mx);
      float alpha = __expf(mrun[r] - mnew);
      mrun[r] = mnew;
      float rs = 0.f;
      for (int nt = 0; nt < 4; nt++) {
        float e = __expf(mvv[nt][r] - mnew) * mk[nt];
        rs += e;
        sPw[(quad * 4 + r) * 72 + nt * 16 + lm] = (f16)e;
      }
      for (int d = 1; d < 16; d <<= 1) rs += __shfl_xor(rs, d, 64);
      lrun[r] = lrun[r] * alpha + rs;
      for (int vt = 0; vt < 4; vt++) oAcc[vt][r] *= alpha;
    }
    // same-wave sP RAW is lgkmcnt-ordered; no cross-wave hazard -> no barrier here
    f16x8 pa0 = *(const f16x8*)(sPw + lm * 72 + quad * 8);
    f16x8 pa1 = *(const f16x8*)(sPw + lm * 72 + 32 + quad * 8);
    for (int vt = 0; vt < 4; vt++) {
      const f16* vr = sVT + (vt * 16 + lm) * 64;
      f16x8 vb0f = *(const f16x8*)(vr + ((quad * 8) ^ swl));
      f16x8 vb1f = *(const f16x8*)(vr + ((32 + quad * 8) ^ swl));
      oAcc[vt] = __builtin_amdgcn_mfma_f32_16x16x32_f16(pa0, vb0f, oAcc[vt], 0, 0, 0);
      oAcc[vt] = __builtin_amdgcn_mfma_f32_16x16x32_f16(pa1, vb1f, oAcc[vt], 0, 0, 0);
    }
  }
  for (int r = 0; r < 4; r++) {
    float l = lrun[r];
    l += (l == 0.f) ? 1.f : 0.f;
    float inv = 1.f / l;
    long row = tok0 + qt * 64 + wid * 16 + quad * 4 + r;
    for (int vt = 0; vt < 4; vt++)
      out[row * 768 + hh * 64 + vt * 16 + lm] = (f16)(oAcc[vt][r] * inv);
  }
}

extern "C" void kernel_launch(void* const* d_in, const int* in_sizes, int n_in,
                              void* d_out, int out_size, void* d_ws, size_t ws_size,
                              hipStream_t stream) {
  const int* ids   = (const int*)d_in[0];
  const int* amask = (const int*)d_in[1];
  const void* we  = d_in[2];
  const void* pe  = d_in[3];
  const void* te  = d_in[4];
  const void* elw = d_in[5];
  const void* elb = d_in[6];
  const void* Wq  = d_in[7];
  const void* bq  = d_in[8];
  const void* Wk  = d_in[9];
  const void* bk  = d_in[10];
  const void* Wv  = d_in[11];
  const void* bv  = d_in[12];
  const void* Wo  = d_in[13];
  const void* bo  = d_in[14];
  const void* l1w = d_in[15];
  const void* l1b = d_in[16];
  const void* Wf1 = d_in[17];
  const void* bf1 = d_in[18];
  const void* Wf2 = d_in[19];
  const void* bf2 = d_in[20];
  const void* l2w = d_in[21];
  const void* l2b = d_in[22];
  (void)in_sizes; (void)n_in; (void)out_size; (void)ws_size;

  // workspace plan (~102.6 MB)
  char* p = (char*)d_ws;
  auto alloc = [&](size_t bytes) { char* r = p; p += (bytes + 255) & ~(size_t)255; return r; };
  int* dflag  = (int*)alloc(256);
  f16* wt     = (f16*)alloc(9216ll * 768 * 2);        // per-layer transposed weights
  float* bqkv = (float*)alloc(12 * 2304 * 4);
  float* bo_f = (float*)alloc(12 * 768 * 4);
  float* bf1f = (float*)alloc(12 * 3072 * 4);
  float* bf2f = (float*)alloc(12 * 768 * 4);
  f16* hbuf  = (f16*)alloc(8192ll * 768 * 2);
  f16* h1buf = (f16*)alloc(8192ll * 768 * 2);
  f16* tmp   = (f16*)alloc(8192ll * 768 * 2);         // doubles as vT during attention
  f16* big   = (f16*)alloc(8192ll * 3072 * 2);        // qkvb / ffn1b (+aobuf in tail)
  f16* qkvb  = big;
  f16* ffn1b = big;
  f16* aobuf = big + 8192ll * 2304;                   // tail: free during attention

  detect_dtype<<<1, 256, 0, stream>>>((const u16*)we, dflag);
  prep_bias<<<144, 256, 0, stream>>>(bq, bk, bv, bo, bf1, bf2, bqkv, bo_f, bf1f, bf2f, dflag);
  embed_ln<<<2048, 256, 0, stream>>>(ids, we, pe, te, elw, elb, hbuf, dflag);

  for (int l = 0; l < 12; ++l) {
    transpose_layer<<<6912, 256, 0, stream>>>(Wq, Wk, Wv, Wo, Wf1, Wf2, wt, l, dflag);
    gemm_bt<0><<<dim3(18, 64), 256, 0, stream>>>(hbuf, wt, bqkv + l * 2304,
                                                 nullptr, qkvb, 8192, 2304, 768);
    vtrans<<<dim3(8, 12, 16), 256, 0, stream>>>(qkvb, tmp);
    attn_kern<<<dim3(192, 8), 256, 0, stream>>>(qkvb, tmp, amask, aobuf);
    gemm_bt<2><<<dim3(6, 64), 256, 0, stream>>>(aobuf, wt + 1769472, bo_f + l * 768,
                                                hbuf, tmp, 8192, 768, 768);
    ln_row<0><<<2048, 256, 0, stream>>>(tmp, l1w, l1b, l, h1buf, nullptr, dflag);
    gemm_bt<1><<<dim3(24, 64), 256, 0, stream>>>(h1buf, wt + 2359296, bf1f + l * 3072,
                                                 nullptr, ffn1b, 8192, 3072, 768);
    gemm_bt<2><<<dim3(6, 64), 256, 0, stream>>>(ffn1b, wt + 4718592, bf2f + l * 768,
                                                h1buf, tmp, 8192, 768, 3072);
    if (l < 11)
      ln_row<0><<<2048, 256, 0, stream>>>(tmp, l2w, l2b, l, hbuf, nullptr, dflag);
    else
      ln_row<1><<<2048, 256, 0, stream>>>(tmp, l2w, l2b, l, nullptr, d_out, dflag);
  }
}

// Round 7
// 3707.237 us; speedup vs baseline: 1.1555x; 1.0121x over previous
//
#include <hip/hip_runtime.h>
#include <cstdint>
#include <cstddef>

typedef _Float16 f16;
typedef unsigned short u16;
typedef _Float16 f16x8 __attribute__((ext_vector_type(8)));
typedef float f32x4 __attribute__((ext_vector_type(4)));

#define DEV __device__ __forceinline__

DEV float b2f(u16 u) { union { float f; unsigned int i; } x; x.i = ((unsigned int)u) << 16; return x.f; }
DEV u16 f2b(float f) {
  union { float f; unsigned int i; } x; x.f = f;
  unsigned int u = x.i;
  return (u16)((u + 0x7FFFu + ((u >> 16) & 1u)) >> 16);
}
// dtype-adaptive float input read: isb=1 -> data is bf16, isb=0 -> data is fp32
DEV float ldf(const void* p, long i, int isb) {
  return isb ? b2f(((const u16*)p)[i]) : ((const float*)p)[i];
}

// async global->LDS, 16B per lane; LDS dest must be wave-uniform (HW adds lane*16)
DEV void gl_lds16(const f16* g, f16* l) {
  __builtin_amdgcn_global_load_lds((const __attribute__((address_space(1))) void*)g,
                                   (__attribute__((address_space(3))) void*)l, 16, 0, 0);
}

// Abramowitz-Stegun 7.1.26 erf: |err| <= 1.5e-7 (far below f16 ulp), ~15 VALU + exp + rcp
DEV float fast_erf(float x) {
  float ax = fabsf(x);
  float t = __builtin_amdgcn_rcpf(1.f + 0.3275911f * ax);
  float p = t * (0.254829592f + t * (-0.284496736f +
            t * (1.421413741f + t * (-1.453152027f + t * 1.061405429f))));
  float e = 1.f - p * __expf(-ax * ax);
  return copysignf(e, x);
}

// ---------- input dtype detector: 1 = bf16, 0 = fp32 ----------
__global__ void detect_dtype(const u16* __restrict__ we, int* __restrict__ flag) {
  __shared__ int cnt;
  if (threadIdx.x == 0) cnt = 0;
  __syncthreads();
  int ok = 0;
  for (int i = 0; i < 16; i++) {
    u16 u = we[threadIdx.x * 16 + i];
    int e = (u >> 7) & 0xFF;  // bf16 exponent field
    if (e >= 90 && e <= 130) ok++;  // N(0,0.02) bf16 lives here; fp32 low-halves mostly don't
  }
  atomicAdd(&cnt, ok);
  __syncthreads();
  if (threadIdx.x == 0) *flag = (cnt > 3481) ? 1 : 0;  // >85% of 4096
}

// ---------- fused per-layer weight transpose: [R][C] -> f16 [C][R] ----------
__global__ __launch_bounds__(256) void transpose_layer(const void* __restrict__ Wq, const void* __restrict__ Wk,
                                                       const void* __restrict__ Wv, const void* __restrict__ Wo,
                                                       const void* __restrict__ Wf1, const void* __restrict__ Wf2,
                                                       f16* __restrict__ wt, int l, const int* __restrict__ dflag) {
  __shared__ f16 tile[32][33];
  int isb = *dflag;
  int bid = blockIdx.x;
  const void* ip;
  f16* op;
  int R, C, rblk, cblk;
  long ioff;
  if (bid < 2304) {
    int which = bid / 576, t = bid % 576;
    R = 768; C = 768;
    cblk = t % 24; rblk = t / 24;
    const void* bases[4] = {Wq, Wk, Wv, Wo};
    ip = bases[which];
    ioff = (long)l * 768 * 768;
    long outs[4] = {0, 589824, 1179648, 1769472};
    op = wt + outs[which];
  } else if (bid < 4608) {
    int t = bid - 2304;
    R = 768; C = 3072;
    cblk = t % 96; rblk = t / 96;
    ip = Wf1; ioff = (long)l * 768 * 3072;
    op = wt + 2359296;
  } else {
    int t = bid - 4608;
    R = 3072; C = 768;
    cblk = t % 24; rblk = t / 24;
    ip = Wf2; ioff = (long)l * 3072 * 768;
    op = wt + 4718592;
  }
  int r0 = rblk * 32, c0 = cblk * 32;
  int tx = threadIdx.x & 31, ty = threadIdx.x >> 5;  // 32 x 8
  for (int i = 0; i < 4; i++) {
    int r = r0 + ty + 8 * i;
    tile[ty + 8 * i][tx] = (f16)ldf(ip, ioff + (long)r * C + c0 + tx, isb);
  }
  __syncthreads();
  for (int i = 0; i < 4; i++) {
    int c = c0 + ty + 8 * i;
    op[(long)c * R + r0 + tx] = tile[tx][ty + 8 * i];
  }
}

// ---------- bias prep -> fp32, qkv fused (all 12 layers) ----------
__global__ void prep_bias(const void* bq, const void* bk, const void* bv, const void* bo,
                          const void* bf1, const void* bf2,
                          float* bqkv, float* bo_f, float* bf1f, float* bf2f, const int* dflag) {
  int isb = *dflag;
  int i = blockIdx.x * 256 + threadIdx.x;
  if (i < 12 * 768) {
    int l = i / 768, j = i % 768;
    bqkv[l * 2304 + j] = ldf(bq, i, isb);
    bqkv[l * 2304 + 768 + j] = ldf(bk, i, isb);
    bqkv[l * 2304 + 1536 + j] = ldf(bv, i, isb);
    bo_f[i] = ldf(bo, i, isb);
    bf2f[i] = ldf(bf2, i, isb);
  }
  if (i < 12 * 3072) bf1f[i] = ldf(bf1, i, isb);
}

// ---------- embedding + LN, wave per token ----------
__global__ __launch_bounds__(256) void embed_ln(const int* __restrict__ ids, const void* __restrict__ we,
                                                const void* __restrict__ pe, const void* __restrict__ te,
                                                const void* __restrict__ lw, const void* __restrict__ lb,
                                                f16* __restrict__ h, const int* __restrict__ dflag) {
  int isb = *dflag;
  int wid = threadIdx.x >> 6, lane = threadIdx.x & 63;
  long t = (long)blockIdx.x * 4 + wid;
  int s = (int)(t & 511);
  long id = ids[t];
  float v[12], s1 = 0.f, s2 = 0.f;
  for (int i = 0; i < 12; i++) {
    int j = i * 64 + lane;
    float f = ldf(we, id * 768 + j, isb) + ldf(pe, (long)s * 768 + j, isb) + ldf(te, j, isb);
    v[i] = f; s1 += f; s2 += f * f;
  }
  for (int d = 1; d < 64; d <<= 1) { s1 += __shfl_xor(s1, d, 64); s2 += __shfl_xor(s2, d, 64); }
  float mean = s1 * (1.f / 768.f);
  float var = fmaxf(s2 * (1.f / 768.f) - mean * mean, 0.f);
  float inv = rsqrtf(var + 1e-12f);
  for (int i = 0; i < 12; i++) {
    int j = i * 64 + lane;
    h[t * 768 + j] = (f16)((v[i] - mean) * inv * ldf(lw, j, isb) + ldf(lb, j, isb));
  }
}

// ---------- layernorm of f16 row; lw/lb indexed at [l][768]; FINAL=1 writes d_out ----------
template <int FINAL>
__global__ __launch_bounds__(256) void ln_row(const f16* __restrict__ x, const void* __restrict__ lw,
                                              const void* __restrict__ lb, int l, f16* __restrict__ outf,
                                              void* __restrict__ outg, const int* __restrict__ dflag) {
  int isb = *dflag;
  long poff = (long)l * 768;
  int wid = threadIdx.x >> 6, lane = threadIdx.x & 63;
  long t = (long)blockIdx.x * 4 + wid;
  const f16* xr = x + t * 768;
  float v[12], s1 = 0.f, s2 = 0.f;
  for (int i = 0; i < 12; i++) {
    float f = (float)xr[i * 64 + lane];
    v[i] = f; s1 += f; s2 += f * f;
  }
  for (int d = 1; d < 64; d <<= 1) { s1 += __shfl_xor(s1, d, 64); s2 += __shfl_xor(s2, d, 64); }
  float mean = s1 * (1.f / 768.f);
  float var = fmaxf(s2 * (1.f / 768.f) - mean * mean, 0.f);
  float inv = rsqrtf(var + 1e-12f);
  for (int i = 0; i < 12; i++) {
    int j = i * 64 + lane;
    float o = (v[i] - mean) * inv * ldf(lw, poff + j, isb) + ldf(lb, poff + j, isb);
    long idx = t * 768 + j;
    if (FINAL) {
      if (isb) ((u16*)outg)[idx] = f2b(o);
      else     ((float*)outg)[idx] = o;
    } else {
      outf[idx] = (f16)o;
    }
  }
}

// ---------- 128x128-tile GEMM: C[M,N] = A[M,K] @ Bt[N,K]^T + bias ----------
// 2-phase double-buffered pipeline (T3 minimum): issue next tile's global_load_lds
// BEFORE computing current tile; one __syncthreads per K-step (its builtin
// vmcnt(0)+lgkmcnt(0) drain IS the "vmcnt(0); barrier" of the recipe).
// EPI: 0 = plain, 1 = exact gelu (A&S erf), 2 = += resid
template <int EPI>
__global__ __launch_bounds__(256) void gemm_bt(const f16* __restrict__ A, const f16* __restrict__ Bt,
                                               const float* __restrict__ bias, const f16* __restrict__ resid,
                                               f16* __restrict__ C, int M, int N, int K) {
  __shared__ f16 lA[2][128 * 32];
  __shared__ f16 lB[2][128 * 32];
  int tid = threadIdx.x, lane = tid & 63;
  int wid = tid >> 6;
  int lm = lane & 15, quad = lane >> 4;
  int wm = wid & 1, wn = wid >> 1;

  // XCD-aware chunked swizzle: consecutive work ids (n fastest) land on ONE XCD
  int gx = gridDim.x;
  int nwg = gx * gridDim.y;
  int flat = blockIdx.y * gx + blockIdx.x;
  int wgid = (flat & 7) * (nwg >> 3) + (flat >> 3);
  long m0 = (long)(wgid / gx) * 128, n0 = (long)(wgid % gx) * 128;

  f32x4 acc[4][4];
  for (int i = 0; i < 4; i++) for (int j = 0; j < 4; j++) acc[i][j] = (f32x4){0.f, 0.f, 0.f, 0.f};

  // staging: wave w covers rows [w*32, w*32+32); lane i -> row w*32(+16) + i/4, k (i&3)*8
  int srow = lane >> 2;            // 0..15
  int scol = (lane & 3) * 8;       // 0/8/16/24
  const f16* ap0 = A + (m0 + wid * 32 + srow) * (long)K + scol;
  const f16* bp0 = Bt + (n0 + wid * 32 + srow) * (long)K + scol;
  long stride16 = 16 * (long)K;

  auto stage = [&](int buf, int kt) {
    f16* la = lA[buf] + wid * 1024;  // wave-uniform LDS bases
    f16* lb = lB[buf] + wid * 1024;
    gl_lds16(ap0 + kt, la);
    gl_lds16(ap0 + stride16 + kt, la + 512);
    gl_lds16(bp0 + kt, lb);
    gl_lds16(bp0 + stride16 + kt, lb + 512);
  };

  stage(0, 0);
  int cur = 0;
  for (int kt = 0; kt < K; kt += 32) {
    __syncthreads();               // vmcnt(0)+lgkmcnt(0)+barrier: buf[cur] loads landed,
                                   // all waves done reading buf[cur^1] (lgkm drained pre-MFMA)
    if (kt + 32 < K) stage(cur ^ 1, kt + 32);  // prefetch next tile under this tile's compute
    f16x8 af[4], bf[4];
    for (int mi = 0; mi < 4; mi++) af[mi] = *(const f16x8*)(lA[cur] + (wm * 64 + mi * 16 + lm) * 32 + quad * 8);
    for (int ni = 0; ni < 4; ni++) bf[ni] = *(const f16x8*)(lB[cur] + (wn * 64 + ni * 16 + lm) * 32 + quad * 8);
    for (int mi = 0; mi < 4; mi++)
      for (int ni = 0; ni < 4; ni++)
        acc[mi][ni] = __builtin_amdgcn_mfma_f32_16x16x32_f16(af[mi], bf[ni], acc[mi][ni], 0, 0, 0);
    cur ^= 1;
  }

  for (int mi = 0; mi < 4; mi++)
    for (int ni = 0; ni < 4; ni++) {
      long row = m0 + wm * 64 + mi * 16 + quad * 4;
      long col = n0 + wn * 64 + ni * 16 + lm;
      float bv = bias[col];
      for (int r = 0; r < 4; r++) {
        long idx = (row + r) * N + col;
        float v = acc[mi][ni][r] + bv;
        if (EPI == 1) v = 0.5f * v * (1.f + fast_erf(v * 0.70710678118654752f));
        if (EPI == 2) v += (float)resid[idx];
        C[idx] = (f16)v;
      }
    }
}

// ---------- V transpose: qkvb V-part [token][768] -> vT [768][8192] ----------
// block = (stile, head, batch); 64x64 tile via padded LDS
__global__ __launch_bounds__(256) void vtrans(const f16* __restrict__ qkv, f16* __restrict__ vT) {
  __shared__ f16 sT[64 * 72];
  int tid = threadIdx.x;
  int st = blockIdx.x, hh = blockIdx.y, bb = blockIdx.z;
  long t0 = (long)bb * 512 + st * 64;
  int r = tid >> 3, c = tid & 7;  // r 0..31, c = 16B chunk
  const f16* src = qkv + 1536 + (long)hh * 64 + c * 8;
  *(f16x8*)(sT + r * 72 + c * 8)      = *(const f16x8*)(src + (t0 + r) * 2304);
  *(f16x8*)(sT + (r + 32) * 72 + c * 8) = *(const f16x8*)(src + (t0 + r + 32) * 2304);
  __syncthreads();
  int d = tid >> 2, sq = tid & 3;  // d 0..63, sq: 16-token chunk
  f16 tmp[16];
  for (int j = 0; j < 16; j++) tmp[j] = sT[(sq * 16 + j) * 72 + d];
  f16x8* o = (f16x8*)(vT + ((long)hh * 64 + d) * 8192 + t0 + sq * 16);
  o[0] = *(f16x8*)(tmp);
  o[1] = *(f16x8*)(tmp + 8);
}

// ---------- flash attention v2 ----------
// block = (hh + 12*bb, qt): qt-blocks of one head are 192 apart in flat id -> same XCD (L2 reuse).
// K and V^T staged via global_load_lds with XOR-preswizzled source (rule #21), zero write conflicts.
__global__ __launch_bounds__(256) void attn_kern(const f16* __restrict__ qkv, const f16* __restrict__ vT,
                                                 const int* __restrict__ amask, f16* __restrict__ out) {
  __shared__ f16 sK[64 * 64];      // [key][d], XOR-swizzled: col^=(key&7)*8
  __shared__ f16 sVT[64 * 64];     // [d][key], XOR-swizzled: col^=(d&7)*8
  __shared__ f16 sP[4 * 16 * 72];  // per-wave P rows
  __shared__ float sMall[512];
  int tid = threadIdx.x, wid = tid >> 6, lane = tid & 63;
  int lm = lane & 15, quad = lane >> 4;
  int xb = blockIdx.x, qt = blockIdx.y;
  int hh = xb % 12, bb = xb / 12;
  long tok0 = (long)bb * 512;

  sMall[tid] = (float)amask[tok0 + tid];
  sMall[tid + 256] = (float)amask[tok0 + 256 + tid];

  const f16* qrow = qkv + (tok0 + qt * 64 + wid * 16 + lm) * 2304 + hh * 64;
  f16x8 qa0 = *(const f16x8*)(qrow + quad * 8);
  f16x8 qa1 = *(const f16x8*)(qrow + 32 + quad * 8);
  for (int j = 0; j < 8; j++) {
    qa0[j] = (f16)((float)qa0[j] * 0.125f);
    qa1[j] = (f16)((float)qa1[j] * 0.125f);
  }

  f32x4 oAcc[4];
  float mrun[4], lrun[4];
  for (int r = 0; r < 4; r++) { mrun[r] = -1e30f; lrun[r] = 0.f; }
  for (int vt = 0; vt < 4; vt++) oAcc[vt] = (f32x4){0.f, 0.f, 0.f, 0.f};
  f16* sPw = sP + wid * 16 * 72;
  int swl = (lm & 7) * 8;                        // read-side XOR (elems)

  // staging: wave w issues instrs i=2w,2w+1 for K and V^T (8 rows each, 128B/row)
  int i0 = wid * 2;
  int key0 = lane >> 3;                          // 0..7
  int col = ((lane & 7) ^ (lane >> 3)) * 8;      // pre-swizzled source col (elems)
  const f16* kb0 = qkv + 768 + (long)hh * 64 + col;
  const f16* vb0 = vT + ((long)hh * 64) * 8192 + tok0 + col;

  for (int kt = 0; kt < 8; kt++) {
    long j0 = tok0 + kt * 64;
    __syncthreads();  // prior iteration's sK/sVT reads done (also covers sMall first use)
    for (int ii = 0; ii < 2; ii++) {
      int i = i0 + ii;
      int rowi = i * 8 + key0;
      gl_lds16(kb0 + (j0 + rowi) * 2304, sK + i * 512);
      gl_lds16(vb0 + (long)rowi * 8192 + kt * 64, sVT + i * 512);
    }
    __syncthreads();  // vmcnt(0) drain: tiles visible

    f32x4 sAcc[4];
    for (int nt = 0; nt < 4; nt++) {
      const f16* kr = sK + (nt * 16 + lm) * 64;
      f16x8 b0 = *(const f16x8*)(kr + ((quad * 8) ^ swl));
      f16x8 b1 = *(const f16x8*)(kr + ((32 + quad * 8) ^ swl));
      f32x4 z = (f32x4){0.f, 0.f, 0.f, 0.f};
      z = __builtin_amdgcn_mfma_f32_16x16x32_f16(qa0, b0, z, 0, 0, 0);
      z = __builtin_amdgcn_mfma_f32_16x16x32_f16(qa1, b1, z, 0, 0, 0);
      sAcc[nt] = z;
    }
    float mk[4];
    for (int nt = 0; nt < 4; nt++) mk[nt] = sMall[kt * 64 + nt * 16 + lm];
    float mvv[4][4];
    for (int nt = 0; nt < 4; nt++)
      for (int r = 0; r < 4; r++) mvv[nt][r] = sAcc[nt][r] * mk[nt];
    for (int r = 0; r < 4; r++) {
      float mx = fmaxf(fmaxf(mvv[0][r], mvv[1][r]), fmaxf(mvv[2][r], mvv[3][r]));
      for (int d = 1; d < 16; d <<= 1) mx = fmaxf(mx, __shfl_xor(mx, d, 64));
      float mnew = fmaxf(mrun[r], mx);
      float alpha = __expf(mrun[r] - mnew);
      mrun[r] = mnew;
      float rs = 0.f;
      for (int nt = 0; nt < 4; nt++) {
        float e = __expf(mvv[nt][r] - mnew) * mk[nt];
        rs += e;
        sPw[(quad * 4 + r) * 72 + nt * 16 + lm] = (f16)e;
      }
      for (int d = 1; d < 16; d <<= 1) rs += __shfl_xor(rs, d, 64);
      lrun[r] = lrun[r] * alpha + rs;
      for (int vt = 0; vt < 4; vt++) oAcc[vt][r] *= alpha;
    }
    // same-wave sP RAW is lgkmcnt-ordered; no cross-wave hazard -> no barrier here
    f16x8 pa0 = *(const f16x8*)(sPw + lm * 72 + quad * 8);
    f16x8 pa1 = *(const f16x8*)(sPw + lm * 72 + 32 + quad * 8);
    for (int vt = 0; vt < 4; vt++) {
      const f16* vr = sVT + (vt * 16 + lm) * 64;
      f16x8 vb0f = *(const f16x8*)(vr + ((quad * 8) ^ swl));
      f16x8 vb1f = *(const f16x8*)(vr + ((32 + quad * 8) ^ swl));
      oAcc[vt] = __builtin_amdgcn_mfma_f32_16x16x32_f16(pa0, vb0f, oAcc[vt], 0, 0, 0);
      oAcc[vt] = __builtin_amdgcn_mfma_f32_16x16x32_f16(pa1, vb1f, oAcc[vt], 0, 0, 0);
    }
  }
  for (int r = 0; r < 4; r++) {
    float l = lrun[r];
    l += (l == 0.f) ? 1.f : 0.f;
    float inv = 1.f / l;
    long row = tok0 + qt * 64 + wid * 16 + quad * 4 + r;
    for (int vt = 0; vt < 4; vt++)
      out[row * 768 + hh * 64 + vt * 16 + lm] = (f16)(oAcc[vt][r] * inv);
  }
}

extern "C" void kernel_launch(void* const* d_in, const int* in_sizes, int n_in,
                              void* d_out, int out_size, void* d_ws, size_t ws_size,
                              hipStream_t stream) {
  const int* ids   = (const int*)d_in[0];
  const int* amask = (const int*)d_in[1];
  const void* we  = d_in[2];
  const void* pe  = d_in[3];
  const void* te  = d_in[4];
  const void* elw = d_in[5];
  const void* elb = d_in[6];
  const void* Wq  = d_in[7];
  const void* bq  = d_in[8];
  const void* Wk  = d_in[9];
  const void* bk  = d_in[10];
  const void* Wv  = d_in[11];
  const void* bv  = d_in[12];
  const void* Wo  = d_in[13];
  const void* bo  = d_in[14];
  const void* l1w = d_in[15];
  const void* l1b = d_in[16];
  const void* Wf1 = d_in[17];
  const void* bf1 = d_in[18];
  const void* Wf2 = d_in[19];
  const void* bf2 = d_in[20];
  const void* l2w = d_in[21];
  const void* l2b = d_in[22];
  (void)in_sizes; (void)n_in; (void)out_size; (void)ws_size;

  // workspace plan (~102.6 MB)
  char* p = (char*)d_ws;
  auto alloc = [&](size_t bytes) { char* r = p; p += (bytes + 255) & ~(size_t)255; return r; };
  int* dflag  = (int*)alloc(256);
  f16* wt     = (f16*)alloc(9216ll * 768 * 2);        // per-layer transposed weights
  float* bqkv = (float*)alloc(12 * 2304 * 4);
  float* bo_f = (float*)alloc(12 * 768 * 4);
  float* bf1f = (float*)alloc(12 * 3072 * 4);
  float* bf2f = (float*)alloc(12 * 768 * 4);
  f16* hbuf  = (f16*)alloc(8192ll * 768 * 2);
  f16* h1buf = (f16*)alloc(8192ll * 768 * 2);
  f16* tmp   = (f16*)alloc(8192ll * 768 * 2);         // doubles as vT during attention
  f16* big   = (f16*)alloc(8192ll * 3072 * 2);        // qkvb / ffn1b (+aobuf in tail)
  f16* qkvb  = big;
  f16* ffn1b = big;
  f16* aobuf = big + 8192ll * 2304;                   // tail: free during attention

  detect_dtype<<<1, 256, 0, stream>>>((const u16*)we, dflag);
  prep_bias<<<144, 256, 0, stream>>>(bq, bk, bv, bo, bf1, bf2, bqkv, bo_f, bf1f, bf2f, dflag);
  embed_ln<<<2048, 256, 0, stream>>>(ids, we, pe, te, elw, elb, hbuf, dflag);

  for (int l = 0; l < 12; ++l) {
    transpose_layer<<<6912, 256, 0, stream>>>(Wq, Wk, Wv, Wo, Wf1, Wf2, wt, l, dflag);
    gemm_bt<0><<<dim3(18, 64), 256, 0, stream>>>(hbuf, wt, bqkv + l * 2304,
                                                 nullptr, qkvb, 8192, 2304, 768);
    vtrans<<<dim3(8, 12, 16), 256, 0, stream>>>(qkvb, tmp);
    attn_kern<<<dim3(192, 8), 256, 0, stream>>>(qkvb, tmp, amask, aobuf);
    gemm_bt<2><<<dim3(6, 64), 256, 0, stream>>>(aobuf, wt + 1769472, bo_f + l * 768,
                                                hbuf, tmp, 8192, 768, 768);
    ln_row<0><<<2048, 256, 0, stream>>>(tmp, l1w, l1b, l, h1buf, nullptr, dflag);
    gemm_bt<1><<<dim3(24, 64), 256, 0, stream>>>(h1buf, wt + 2359296, bf1f + l * 3072,
                                                 nullptr, ffn1b, 8192, 3072, 768);
    gemm_bt<2><<<dim3(6, 64), 256, 0, stream>>>(ffn1b, wt + 4718592, bf2f + l * 768,
                                                h1buf, tmp, 8192, 768, 3072);
    if (l < 11)
      ln_row<0><<<2048, 256, 0, stream>>>(tmp, l2w, l2b, l, hbuf, nullptr, dflag);
    else
      ln_row<1><<<2048, 256, 0, stream>>>(tmp, l2w, l2b, l, nullptr, d_out, dflag);
  }
}

// Round 8
// 3515.199 us; speedup vs baseline: 1.2187x; 1.0546x over previous
//
#include <hip/hip_runtime.h>
#include <cstdint>
#include <cstddef>

typedef _Float16 f16;
typedef unsigned short u16;
typedef _Float16 f16x8 __attribute__((ext_vector_type(8)));
typedef _Float16 f16x4 __attribute__((ext_vector_type(4)));
typedef float f32x4 __attribute__((ext_vector_type(4)));

#define DEV __device__ __forceinline__

DEV float b2f(u16 u) { union { float f; unsigned int i; } x; x.i = ((unsigned int)u) << 16; return x.f; }
DEV u16 f2b(float f) {
  union { float f; unsigned int i; } x; x.f = f;
  unsigned int u = x.i;
  return (u16)((u + 0x7FFFu + ((u >> 16) & 1u)) >> 16);
}
// dtype-adaptive float input read: isb=1 -> data is bf16, isb=0 -> data is fp32
DEV float ldf(const void* p, long i, int isb) {
  return isb ? b2f(((const u16*)p)[i]) : ((const float*)p)[i];
}

// async global->LDS, 16B per lane; LDS dest must be wave-uniform (HW adds lane*16)
DEV void gl_lds16(const f16* g, f16* l) {
  __builtin_amdgcn_global_load_lds((const __attribute__((address_space(1))) void*)g,
                                   (__attribute__((address_space(3))) void*)l, 16, 0, 0);
}

// Abramowitz-Stegun 7.1.26 erf: |err| <= 1.5e-7 (far below f16 ulp), ~15 VALU + exp + rcp
DEV float fast_erf(float x) {
  float ax = fabsf(x);
  float t = __builtin_amdgcn_rcpf(1.f + 0.3275911f * ax);
  float p = t * (0.254829592f + t * (-0.284496736f +
            t * (1.421413741f + t * (-1.453152027f + t * 1.061405429f))));
  float e = 1.f - p * __expf(-ax * ax);
  return copysignf(e, x);
}

// ---------- input dtype detector: 1 = bf16, 0 = fp32 ----------
__global__ void detect_dtype(const u16* __restrict__ we, int* __restrict__ flag) {
  __shared__ int cnt;
  if (threadIdx.x == 0) cnt = 0;
  __syncthreads();
  int ok = 0;
  for (int i = 0; i < 16; i++) {
    u16 u = we[threadIdx.x * 16 + i];
    int e = (u >> 7) & 0xFF;  // bf16 exponent field
    if (e >= 90 && e <= 130) ok++;  // N(0,0.02) bf16 lives here; fp32 low-halves mostly don't
  }
  atomicAdd(&cnt, ok);
  __syncthreads();
  if (threadIdx.x == 0) *flag = (cnt > 3481) ? 1 : 0;  // >85% of 4096
}

// ---------- fused per-layer weight transpose: [R][C] -> f16 [C][R], 4-wide vectorized ----------
__global__ __launch_bounds__(256) void transpose_layer(const void* __restrict__ Wq, const void* __restrict__ Wk,
                                                       const void* __restrict__ Wv, const void* __restrict__ Wo,
                                                       const void* __restrict__ Wf1, const void* __restrict__ Wf2,
                                                       f16* __restrict__ wt, int l, const int* __restrict__ dflag) {
  __shared__ f16 tile[32][33];
  int isb = *dflag;
  int bid = blockIdx.x;
  const void* ip;
  f16* op;
  int R, C, rblk, cblk;
  long ioff;
  if (bid < 2304) {
    int which = bid / 576, t = bid % 576;
    R = 768; C = 768;
    cblk = t % 24; rblk = t / 24;
    const void* bases[4] = {Wq, Wk, Wv, Wo};
    ip = bases[which];
    ioff = (long)l * 768 * 768;
    long outs[4] = {0, 589824, 1179648, 1769472};
    op = wt + outs[which];
  } else if (bid < 4608) {
    int t = bid - 2304;
    R = 768; C = 3072;
    cblk = t % 96; rblk = t / 96;
    ip = Wf1; ioff = (long)l * 768 * 3072;
    op = wt + 2359296;
  } else {
    int t = bid - 4608;
    R = 3072; C = 768;
    cblk = t % 24; rblk = t / 24;
    ip = Wf2; ioff = (long)l * 3072 * 768;
    op = wt + 4718592;
  }
  int r0 = rblk * 32, c0 = cblk * 32;
  int tid = threadIdx.x;
  // load: thread -> (row, 4-col group), vector 4
  int row = tid >> 3, cg = (tid & 7) * 4;
  long base = ioff + (long)(r0 + row) * C + c0 + cg;
  if (isb) {
    ushort4 u = *(const ushort4*)((const u16*)ip + base);
    tile[row][cg + 0] = (f16)b2f(u.x);
    tile[row][cg + 1] = (f16)b2f(u.y);
    tile[row][cg + 2] = (f16)b2f(u.z);
    tile[row][cg + 3] = (f16)b2f(u.w);
  } else {
    float4 f = *(const float4*)((const float*)ip + base);
    tile[row][cg + 0] = (f16)f.x;
    tile[row][cg + 1] = (f16)f.y;
    tile[row][cg + 2] = (f16)f.z;
    tile[row][cg + 3] = (f16)f.w;
  }
  __syncthreads();
  // store: thread -> (col, 4-row group), vector 4 (8B, aligned: R%4==0, r0%32==0)
  int col = tid >> 3, rg = (tid & 7) * 4;
  f16x4 v = (f16x4){tile[rg + 0][col], tile[rg + 1][col], tile[rg + 2][col], tile[rg + 3][col]};
  *(f16x4*)(op + (long)(c0 + col) * R + r0 + rg) = v;
}

// ---------- bias prep -> fp32, qkv fused (all 12 layers) ----------
__global__ void prep_bias(const void* bq, const void* bk, const void* bv, const void* bo,
                          const void* bf1, const void* bf2,
                          float* bqkv, float* bo_f, float* bf1f, float* bf2f, const int* dflag) {
  int isb = *dflag;
  int i = blockIdx.x * 256 + threadIdx.x;
  if (i < 12 * 768) {
    int l = i / 768, j = i % 768;
    bqkv[l * 2304 + j] = ldf(bq, i, isb);
    bqkv[l * 2304 + 768 + j] = ldf(bk, i, isb);
    bqkv[l * 2304 + 1536 + j] = ldf(bv, i, isb);
    bo_f[i] = ldf(bo, i, isb);
    bf2f[i] = ldf(bf2, i, isb);
  }
  if (i < 12 * 3072) bf1f[i] = ldf(bf1, i, isb);
}

// ---------- embedding + LN, wave per token ----------
__global__ __launch_bounds__(256) void embed_ln(const int* __restrict__ ids, const void* __restrict__ we,
                                                const void* __restrict__ pe, const void* __restrict__ te,
                                                const void* __restrict__ lw, const void* __restrict__ lb,
                                                f16* __restrict__ h, const int* __restrict__ dflag) {
  int isb = *dflag;
  int wid = threadIdx.x >> 6, lane = threadIdx.x & 63;
  long t = (long)blockIdx.x * 4 + wid;
  int s = (int)(t & 511);
  long id = ids[t];
  float v[12], s1 = 0.f, s2 = 0.f;
  for (int i = 0; i < 12; i++) {
    int j = i * 64 + lane;
    float f = ldf(we, id * 768 + j, isb) + ldf(pe, (long)s * 768 + j, isb) + ldf(te, j, isb);
    v[i] = f; s1 += f; s2 += f * f;
  }
  for (int d = 1; d < 64; d <<= 1) { s1 += __shfl_xor(s1, d, 64); s2 += __shfl_xor(s2, d, 64); }
  float mean = s1 * (1.f / 768.f);
  float var = fmaxf(s2 * (1.f / 768.f) - mean * mean, 0.f);
  float inv = rsqrtf(var + 1e-12f);
  for (int i = 0; i < 12; i++) {
    int j = i * 64 + lane;
    h[t * 768 + j] = (f16)((v[i] - mean) * inv * ldf(lw, j, isb) + ldf(lb, j, isb));
  }
}

// ---------- layernorm of f16 row; lw/lb indexed at [l][768]; FINAL=1 writes d_out ----------
template <int FINAL>
__global__ __launch_bounds__(256) void ln_row(const f16* __restrict__ x, const void* __restrict__ lw,
                                              const void* __restrict__ lb, int l, f16* __restrict__ outf,
                                              void* __restrict__ outg, const int* __restrict__ dflag) {
  int isb = *dflag;
  long poff = (long)l * 768;
  int wid = threadIdx.x >> 6, lane = threadIdx.x & 63;
  long t = (long)blockIdx.x * 4 + wid;
  const f16* xr = x + t * 768;
  float v[12], s1 = 0.f, s2 = 0.f;
  for (int i = 0; i < 12; i++) {
    float f = (float)xr[i * 64 + lane];
    v[i] = f; s1 += f; s2 += f * f;
  }
  for (int d = 1; d < 64; d <<= 1) { s1 += __shfl_xor(s1, d, 64); s2 += __shfl_xor(s2, d, 64); }
  float mean = s1 * (1.f / 768.f);
  float var = fmaxf(s2 * (1.f / 768.f) - mean * mean, 0.f);
  float inv = rsqrtf(var + 1e-12f);
  for (int i = 0; i < 12; i++) {
    int j = i * 64 + lane;
    float o = (v[i] - mean) * inv * ldf(lw, poff + j, isb) + ldf(lb, poff + j, isb);
    long idx = t * 768 + j;
    if (FINAL) {
      if (isb) ((u16*)outg)[idx] = f2b(o);
      else     ((float*)outg)[idx] = o;
    } else {
      outf[idx] = (f16)o;
    }
  }
}

// ---------- 128x128-tile GEMM: C[M,N] = A[M,K] @ Bt[N,K]^T + bias ----------
// 3-deep pipeline with COUNTED vmcnt (T4): raw s_barrier + s_waitcnt vmcnt(8/4/0)
// keeps 2 tiles of loads in flight across barriers (each load gets ~2 compute
// phases to land, vs drain-0's 1). Hazards: per-wave vmcnt waits own loads,
// barrier-A promotes to all-wave; barrier-B before re-stage (ds_reads consumed
// by MFMA before barrier => complete).  EPI: 0 plain, 1 gelu (A&S erf), 2 +=resid
template <int EPI>
__global__ __launch_bounds__(256) void gemm_bt(const f16* __restrict__ A, const f16* __restrict__ Bt,
                                               const float* __restrict__ bias, const f16* __restrict__ resid,
                                               f16* __restrict__ C, int M, int N, int K) {
  __shared__ f16 lA[3][128 * 32];
  __shared__ f16 lB[3][128 * 32];
  int tid = threadIdx.x, lane = tid & 63;
  int wid = tid >> 6;
  int lm = lane & 15, quad = lane >> 4;
  int wm = wid & 1, wn = wid >> 1;

  // XCD-aware chunked swizzle: consecutive work ids (n fastest) land on ONE XCD
  int gx = gridDim.x;
  int nwg = gx * gridDim.y;
  int flat = blockIdx.y * gx + blockIdx.x;
  int wgid = (flat & 7) * (nwg >> 3) + (flat >> 3);
  long m0 = (long)(wgid / gx) * 128, n0 = (long)(wgid % gx) * 128;

  f32x4 acc[4][4];
  for (int i = 0; i < 4; i++) for (int j = 0; j < 4; j++) acc[i][j] = (f32x4){0.f, 0.f, 0.f, 0.f};

  // staging: wave w covers rows [w*32, w*32+32); lane i -> row w*32(+16) + i/4, k (i&3)*8
  int srow = lane >> 2;            // 0..15
  int scol = (lane & 3) * 8;       // 0/8/16/24
  const f16* ap0 = A + (m0 + wid * 32 + srow) * (long)K + scol;
  const f16* bp0 = Bt + (n0 + wid * 32 + srow) * (long)K + scol;
  long stride16 = 16 * (long)K;

  auto stage = [&](int buf, int kt) {
    f16* la = lA[buf] + wid * 1024;  // wave-uniform LDS bases
    f16* lb = lB[buf] + wid * 1024;
    gl_lds16(ap0 + kt, la);
    gl_lds16(ap0 + stride16 + kt, la + 512);
    gl_lds16(bp0 + kt, lb);
    gl_lds16(bp0 + stride16 + kt, lb + 512);
  };

  int nt = K >> 5;                 // >= 24 for all shapes here
  stage(0, 0);
  stage(1, 32);
  stage(2, 64);
  int cb = 0;
  for (int t = 0; t < nt; ++t) {
    int later = nt - 1 - t;        // tiles still in flight beyond this one
    if (later >= 2)      asm volatile("s_waitcnt vmcnt(8)" ::: "memory");
    else if (later == 1) asm volatile("s_waitcnt vmcnt(4)" ::: "memory");
    else                 asm volatile("s_waitcnt vmcnt(0)" ::: "memory");
    __builtin_amdgcn_sched_barrier(0);
    __builtin_amdgcn_s_barrier();  // all waves' tile-t loads landed
    const f16* LA = lA[cb];
    const f16* LB = lB[cb];
    f16x8 af[4], bf[4];
    for (int mi = 0; mi < 4; mi++) af[mi] = *(const f16x8*)(LA + (wm * 64 + mi * 16 + lm) * 32 + quad * 8);
    for (int ni = 0; ni < 4; ni++) bf[ni] = *(const f16x8*)(LB + (wn * 64 + ni * 16 + lm) * 32 + quad * 8);
    for (int mi = 0; mi < 4; mi++)
      for (int ni = 0; ni < 4; ni++)
        acc[mi][ni] = __builtin_amdgcn_mfma_f32_16x16x32_f16(af[mi], bf[ni], acc[mi][ni], 0, 0, 0);
    __builtin_amdgcn_s_barrier();  // all waves done reading buf[cb] (reads consumed pre-barrier)
    if (t + 3 < nt) stage(cb, (t + 3) << 5);
    cb = (cb == 2) ? 0 : cb + 1;
  }

  for (int mi = 0; mi < 4; mi++)
    for (int ni = 0; ni < 4; ni++) {
      long row = m0 + wm * 64 + mi * 16 + quad * 4;
      long col = n0 + wn * 64 + ni * 16 + lm;
      float bv = bias[col];
      for (int r = 0; r < 4; r++) {
        long idx = (row + r) * N + col;
        float v = acc[mi][ni][r] + bv;
        if (EPI == 1) v = 0.5f * v * (1.f + fast_erf(v * 0.70710678118654752f));
        if (EPI == 2) v += (float)resid[idx];
        C[idx] = (f16)v;
      }
    }
}

// ---------- V transpose: qkvb V-part [token][768] -> vT [768][8192] ----------
// block = (stile, head, batch); 64x64 tile via padded LDS
__global__ __launch_bounds__(256) void vtrans(const f16* __restrict__ qkv, f16* __restrict__ vT) {
  __shared__ f16 sT[64 * 72];
  int tid = threadIdx.x;
  int st = blockIdx.x, hh = blockIdx.y, bb = blockIdx.z;
  long t0 = (long)bb * 512 + st * 64;
  int r = tid >> 3, c = tid & 7;  // r 0..31, c = 16B chunk
  const f16* src = qkv + 1536 + (long)hh * 64 + c * 8;
  *(f16x8*)(sT + r * 72 + c * 8)      = *(const f16x8*)(src + (t0 + r) * 2304);
  *(f16x8*)(sT + (r + 32) * 72 + c * 8) = *(const f16x8*)(src + (t0 + r + 32) * 2304);
  __syncthreads();
  int d = tid >> 2, sq = tid & 3;  // d 0..63, sq: 16-token chunk
  f16 tmp[16];
  for (int j = 0; j < 16; j++) tmp[j] = sT[(sq * 16 + j) * 72 + d];
  f16x8* o = (f16x8*)(vT + ((long)hh * 64 + d) * 8192 + t0 + sq * 16);
  o[0] = *(f16x8*)(tmp);
  o[1] = *(f16x8*)(tmp + 8);
}

// ---------- flash attention v2 ----------
// block = (hh + 12*bb, qt): qt-blocks of one head are 192 apart in flat id -> same XCD (L2 reuse).
// K and V^T staged via global_load_lds with XOR-preswizzled source (rule #21), zero write conflicts.
__global__ __launch_bounds__(256) void attn_kern(const f16* __restrict__ qkv, const f16* __restrict__ vT,
                                                 const int* __restrict__ amask, f16* __restrict__ out) {
  __shared__ f16 sK[64 * 64];      // [key][d], XOR-swizzled: col^=(key&7)*8
  __shared__ f16 sVT[64 * 64];     // [d][key], XOR-swizzled: col^=(d&7)*8
  __shared__ f16 sP[4 * 16 * 72];  // per-wave P rows
  __shared__ float sMall[512];
  int tid = threadIdx.x, wid = tid >> 6, lane = tid & 63;
  int lm = lane & 15, quad = lane >> 4;
  int xb = blockIdx.x, qt = blockIdx.y;
  int hh = xb % 12, bb = xb / 12;
  long tok0 = (long)bb * 512;

  sMall[tid] = (float)amask[tok0 + tid];
  sMall[tid + 256] = (float)amask[tok0 + 256 + tid];

  const f16* qrow = qkv + (tok0 + qt * 64 + wid * 16 + lm) * 2304 + hh * 64;
  f16x8 qa0 = *(const f16x8*)(qrow + quad * 8);
  f16x8 qa1 = *(const f16x8*)(qrow + 32 + quad * 8);
  for (int j = 0; j < 8; j++) {
    qa0[j] = (f16)((float)qa0[j] * 0.125f);
    qa1[j] = (f16)((float)qa1[j] * 0.125f);
  }

  f32x4 oAcc[4];
  float mrun[4], lrun[4];
  for (int r = 0; r < 4; r++) { mrun[r] = -1e30f; lrun[r] = 0.f; }
  for (int vt = 0; vt < 4; vt++) oAcc[vt] = (f32x4){0.f, 0.f, 0.f, 0.f};
  f16* sPw = sP + wid * 16 * 72;
  int swl = (lm & 7) * 8;                        // read-side XOR (elems)

  // staging: wave w issues instrs i=2w,2w+1 for K and V^T (8 rows each, 128B/row)
  int i0 = wid * 2;
  int key0 = lane >> 3;                          // 0..7
  int col = ((lane & 7) ^ (lane >> 3)) * 8;      // pre-swizzled source col (elems)
  const f16* kb0 = qkv + 768 + (long)hh * 64 + col;
  const f16* vb0 = vT + ((long)hh * 64) * 8192 + tok0 + col;

  for (int kt = 0; kt < 8; kt++) {
    long j0 = tok0 + kt * 64;
    __syncthreads();  // prior iteration's sK/sVT reads done (also covers sMall first use)
    for (int ii = 0; ii < 2; ii++) {
      int i = i0 + ii;
      int rowi = i * 8 + key0;
      gl_lds16(kb0 + (j0 + rowi) * 2304, sK + i * 512);
      gl_lds16(vb0 + (long)rowi * 8192 + kt * 64, sVT + i * 512);
    }
    __syncthreads();  // vmcnt(0) drain: tiles visible

    f32x4 sAcc[4];
    for (int nt = 0; nt < 4; nt++) {
      const f16* kr = sK + (nt * 16 + lm) * 64;
      f16x8 b0 = *(const f16x8*)(kr + ((quad * 8) ^ swl));
      f16x8 b1 = *(const f16x8*)(kr + ((32 + quad * 8) ^ swl));
      f32x4 z = (f32x4){0.f, 0.f, 0.f, 0.f};
      z = __builtin_amdgcn_mfma_f32_16x16x32_f16(qa0, b0, z, 0, 0, 0);
      z = __builtin_amdgcn_mfma_f32_16x16x32_f16(qa1, b1, z, 0, 0, 0);
      sAcc[nt] = z;
    }
    float mk[4];
    for (int nt = 0; nt < 4; nt++) mk[nt] = sMall[kt * 64 + nt * 16 + lm];
    float mvv[4][4];
    for (int nt = 0; nt < 4; nt++)
      for (int r = 0; r < 4; r++) mvv[nt][r] = sAcc[nt][r] * mk[nt];
    for (int r = 0; r < 4; r++) {
      float mx = fmaxf(fmaxf(mvv[0][r], mvv[1][r]), fmaxf(mvv[2][r], mvv[3][r]));
      for (int d = 1; d < 16; d <<= 1) mx = fmaxf(mx, __shfl_xor(mx, d, 64));
      float mnew = fmaxf(mrun[r], mx);
      float alpha = __expf(mrun[r] - mnew);
      mrun[r] = mnew;
      float rs = 0.f;
      for (int nt = 0; nt < 4; nt++) {
        float e = __expf(mvv[nt][r] - mnew) * mk[nt];
        rs += e;
        sPw[(quad * 4 + r) * 72 + nt * 16 + lm] = (f16)e;
      }
      for (int d = 1; d < 16; d <<= 1) rs += __shfl_xor(rs, d, 64);
      lrun[r] = lrun[r] * alpha + rs;
      for (int vt = 0; vt < 4; vt++) oAcc[vt][r] *= alpha;
    }
    // same-wave sP RAW is lgkmcnt-ordered; no cross-wave hazard -> no barrier here
    f16x8 pa0 = *(const f16x8*)(sPw + lm * 72 + quad * 8);
    f16x8 pa1 = *(const f16x8*)(sPw + lm * 72 + 32 + quad * 8);
    for (int vt = 0; vt < 4; vt++) {
      const f16* vr = sVT + (vt * 16 + lm) * 64;
      f16x8 vb0f = *(const f16x8*)(vr + ((quad * 8) ^ swl));
      f16x8 vb1f = *(const f16x8*)(vr + ((32 + quad * 8) ^ swl));
      oAcc[vt] = __builtin_amdgcn_mfma_f32_16x16x32_f16(pa0, vb0f, oAcc[vt], 0, 0, 0);
      oAcc[vt] = __builtin_amdgcn_mfma_f32_16x16x32_f16(pa1, vb1f, oAcc[vt], 0, 0, 0);
    }
  }
  for (int r = 0; r < 4; r++) {
    float l = lrun[r];
    l += (l == 0.f) ? 1.f : 0.f;
    float inv = 1.f / l;
    long row = tok0 + qt * 64 + wid * 16 + quad * 4 + r;
    for (int vt = 0; vt < 4; vt++)
      out[row * 768 + hh * 64 + vt * 16 + lm] = (f16)(oAcc[vt][r] * inv);
  }
}

extern "C" void kernel_launch(void* const* d_in, const int* in_sizes, int n_in,
                              void* d_out, int out_size, void* d_ws, size_t ws_size,
                              hipStream_t stream) {
  const int* ids   = (const int*)d_in[0];
  const int* amask = (const int*)d_in[1];
  const void* we  = d_in[2];
  const void* pe  = d_in[3];
  const void* te  = d_in[4];
  const void* elw = d_in[5];
  const void* elb = d_in[6];
  const void* Wq  = d_in[7];
  const void* bq  = d_in[8];
  const void* Wk  = d_in[9];
  const void* bk  = d_in[10];
  const void* Wv  = d_in[11];
  const void* bv  = d_in[12];
  const void* Wo  = d_in[13];
  const void* bo  = d_in[14];
  const void* l1w = d_in[15];
  const void* l1b = d_in[16];
  const void* Wf1 = d_in[17];
  const void* bf1 = d_in[18];
  const void* Wf2 = d_in[19];
  const void* bf2 = d_in[20];
  const void* l2w = d_in[21];
  const void* l2b = d_in[22];
  (void)in_sizes; (void)n_in; (void)out_size; (void)ws_size;

  // workspace plan (~102.6 MB)
  char* p = (char*)d_ws;
  auto alloc = [&](size_t bytes) { char* r = p; p += (bytes + 255) & ~(size_t)255; return r; };
  int* dflag  = (int*)alloc(256);
  f16* wt     = (f16*)alloc(9216ll * 768 * 2);        // per-layer transposed weights
  float* bqkv = (float*)alloc(12 * 2304 * 4);
  float* bo_f = (float*)alloc(12 * 768 * 4);
  float* bf1f = (float*)alloc(12 * 3072 * 4);
  float* bf2f = (float*)alloc(12 * 768 * 4);
  f16* hbuf  = (f16*)alloc(8192ll * 768 * 2);
  f16* h1buf = (f16*)alloc(8192ll * 768 * 2);
  f16* tmp   = (f16*)alloc(8192ll * 768 * 2);         // doubles as vT during attention
  f16* big   = (f16*)alloc(8192ll * 3072 * 2);        // qkvb / ffn1b (+aobuf in tail)
  f16* qkvb  = big;
  f16* ffn1b = big;
  f16* aobuf = big + 8192ll * 2304;                   // tail: free during attention

  detect_dtype<<<1, 256, 0, stream>>>((const u16*)we, dflag);
  prep_bias<<<144, 256, 0, stream>>>(bq, bk, bv, bo, bf1, bf2, bqkv, bo_f, bf1f, bf2f, dflag);
  embed_ln<<<2048, 256, 0, stream>>>(ids, we, pe, te, elw, elb, hbuf, dflag);

  for (int l = 0; l < 12; ++l) {
    transpose_layer<<<6912, 256, 0, stream>>>(Wq, Wk, Wv, Wo, Wf1, Wf2, wt, l, dflag);
    gemm_bt<0><<<dim3(18, 64), 256, 0, stream>>>(hbuf, wt, bqkv + l * 2304,
                                                 nullptr, qkvb, 8192, 2304, 768);
    vtrans<<<dim3(8, 12, 16), 256, 0, stream>>>(qkvb, tmp);
    attn_kern<<<dim3(192, 8), 256, 0, stream>>>(qkvb, tmp, amask, aobuf);
    gemm_bt<2><<<dim3(6, 64), 256, 0, stream>>>(aobuf, wt + 1769472, bo_f + l * 768,
                                                hbuf, tmp, 8192, 768, 768);
    ln_row<0><<<2048, 256, 0, stream>>>(tmp, l1w, l1b, l, h1buf, nullptr, dflag);
    gemm_bt<1><<<dim3(24, 64), 256, 0, stream>>>(h1buf, wt + 2359296, bf1f + l * 3072,
                                                 nullptr, ffn1b, 8192, 3072, 768);
    gemm_bt<2><<<dim3(6, 64), 256, 0, stream>>>(ffn1b, wt + 4718592, bf2f + l * 768,
                                                h1buf, tmp, 8192, 768, 3072);
    if (l < 11)
      ln_row<0><<<2048, 256, 0, stream>>>(tmp, l2w, l2b, l, hbuf, nullptr, dflag);
    else
      ln_row<1><<<2048, 256, 0, stream>>>(tmp, l2w, l2b, l, nullptr, d_out, dflag);
  }
}